// Round 8
// baseline (136.445 us; speedup 1.0000x reference)
//
#include <hip/hip_runtime.h>
#include <hip/hip_bf16.h>

#define BB 32
#define CC 128
#define HH 96
#define WW 96
#define BN_EPS 1e-5f

typedef __attribute__((ext_vector_type(8))) short bf16x8_t;
typedef __attribute__((ext_vector_type(4))) float f32x4_t;
typedef __attribute__((ext_vector_type(4), aligned(4))) float f32x4u_t;
typedef __attribute__((ext_vector_type(2))) unsigned int u32x2_t;
typedef __attribute__((ext_vector_type(4))) unsigned int u32x4_t;

// ---------------------------------------------------------------------------
// Prep: W fp32 -> bf16, k-permuted for mfma_f32_16x16x32_bf16 split-k frags
//   storage cidx = kc*32 + g*8 + j  <->  actual c = kc*32 + g*4 + (j&3) + 16*(j>>2)
// Also folds BN to inv/bias.   (unchanged — verified)
// ---------------------------------------------------------------------------
__global__ __launch_bounds__(256)
void prep_kernel(const float* __restrict__ pw,
                 const float* __restrict__ g, const float* __restrict__ b,
                 const float* __restrict__ m, const float* __restrict__ v,
                 unsigned short* __restrict__ wper,
                 float* __restrict__ inv, float* __restrict__ bias)
{
    int t = blockIdx.x * 256 + threadIdx.x;
    if (t < CC * CC) {
        int o = t >> 7, cidx = t & 127;
        int kc = cidx >> 5, r = cidx & 31, gg = r >> 3, j = r & 7;
        int c = kc * 32 + gg * 4 + (j & 3) + 16 * (j >> 2);
        __hip_bfloat16 h = __float2bfloat16(pw[o * CC + c]);
        wper[o * CC + cidx] = *reinterpret_cast<unsigned short*>(&h);
    }
    if (t < CC) {
        float iv = g[t] * rsqrtf(v[t] + BN_EPS);
        inv[t] = iv;
        bias[t] = b[t] - m[t] * iv;
    }
}

// ---------------------------------------------------------------------------
// Kernel A: standalone streaming depthwise 3x3 (R7 structure).
// R8: launch_bounds(256,8) — ~58 live VGPR fits 64; doubles resident waves.
// ---------------------------------------------------------------------------
__global__ __launch_bounds__(256, 8)
void dw_kernel(const float* __restrict__ x, const float* __restrict__ kk,
               unsigned short* __restrict__ xn)
{
    const int u = blockIdx.x * 256 + threadIdx.x;    // 32*128*96*12 units
    const int woct = u % 12;
    int t1 = u / 12;
    const int h = t1 % HH;
    int t2 = t1 / HH;
    const int cs = t2 & 127;
    const int b  = t2 >> 7;

    // storage -> actual channel permutation
    const int kc = cs >> 5, rr = cs & 31, gg = rr >> 3, jj = rr & 7;
    const int c = kc * 32 + gg * 4 + (jj & 3) + 16 * (jj >> 2);

    const int w0 = woct * 8;
    const bool l_edge = (w0 == 0);
    const bool r_edge = (w0 + 8 >= WW);

    const float* plane = x + (size_t)(b * CC + c) * (HH * WW);

    float kw[9];
    {
        const float* kp = kk + (size_t)(b * CC + c) * 9;
        f32x4u_t q0 = *(const f32x4u_t*)(kp);
        f32x4u_t q1 = *(const f32x4u_t*)(kp + 4);
        kw[0]=q0.x; kw[1]=q0.y; kw[2]=q0.z; kw[3]=q0.w;
        kw[4]=q1.x; kw[5]=q1.y; kw[6]=q1.z; kw[7]=q1.w;
        kw[8]=kp[8];
    }

    float xr[3][10];   // cols w0-1 .. w0+8 for rows h-1,h,h+1
    #pragma unroll
    for (int r = 0; r < 3; ++r) {
        const int row = h - 1 + r;
        const bool valid = (row >= 0) && (row < HH);
        const int rrow = row < 0 ? 0 : (row >= HH ? HH - 1 : row);
        const float* rp = plane + rrow * WW + w0;     // 32B aligned
        f32x4_t M0 = *(const f32x4_t*)rp;
        f32x4_t M1 = *(const f32x4_t*)(rp + 4);
        float vl = rp[l_edge ? 0 : -1];
        float vr = rp[r_edge ? 7 : 8];
        xr[r][0] = (valid && !l_edge) ? vl : 0.f;
        xr[r][1] = valid ? M0.x : 0.f;
        xr[r][2] = valid ? M0.y : 0.f;
        xr[r][3] = valid ? M0.z : 0.f;
        xr[r][4] = valid ? M0.w : 0.f;
        xr[r][5] = valid ? M1.x : 0.f;
        xr[r][6] = valid ? M1.y : 0.f;
        xr[r][7] = valid ? M1.z : 0.f;
        xr[r][8] = valid ? M1.w : 0.f;
        xr[r][9] = (valid && !r_edge) ? vr : 0.f;
    }

    u32x4_t pk;
    unsigned pkw[4];
    #pragma unroll
    for (int i = 0; i < 4; ++i) {
        float s0 = 0.f, s1 = 0.f;
        #pragma unroll
        for (int r = 0; r < 3; ++r) {
            #pragma unroll
            for (int t = 0; t < 3; ++t) {
                s0 = fmaf(xr[r][2 * i + t],     kw[r * 3 + t], s0);
                s1 = fmaf(xr[r][2 * i + 1 + t], kw[r * 3 + t], s1);
            }
        }
        __hip_bfloat16 h0b = __float2bfloat16(s0);
        __hip_bfloat16 h1b = __float2bfloat16(s1);
        pkw[i] = (unsigned)*reinterpret_cast<unsigned short*>(&h0b)
               | ((unsigned)*reinterpret_cast<unsigned short*>(&h1b) << 16);
    }
    pk.x = pkw[0]; pk.y = pkw[1]; pk.z = pkw[2]; pk.w = pkw[3];

    unsigned short* dst = xn + ((size_t)(b * CC + cs) * (HH * WW) + h * WW + w0);
    *reinterpret_cast<u32x4_t*>(dst) = pk;    // 16B aligned, coalesced
}

// ---------------------------------------------------------------------------
// Kernel B: pointwise MFMA GEMM + BN + ReLU.
// R8: mfma operand SWAP — mfma(xn_frag, w_frag, acc) gives C[row=pixel][col=o]
//     (A/B lane layouts are symmetric: lane&15 = M/N index, hi = k-chunk, same
//      storage permutation — staging and fragment loads unchanged).
//     Lane then owns o=lane&15 and 4 consecutive w per (pt,t2) -> dwordx4
//     stores (16 per thread, was 64 scalar). launch_bounds(256,4).
// ---------------------------------------------------------------------------
__global__ __launch_bounds__(256, 4)
void pw_kernel(const unsigned short* __restrict__ xn,
               const unsigned short* __restrict__ wper,
               const float* __restrict__ invp, const float* __restrict__ biasp,
               float* __restrict__ out)
{
    __shared__ __align__(16) unsigned char xnb[128 * 256];
    const int tid = threadIdx.x;

    // chunked XCD swizzle (2304 = 8 x 288)
    const unsigned wg  = blockIdx.x;
    const unsigned nid = (wg & 7u) * 288u + (wg >> 3);
    const int tw = nid % 6u;
    const int th = (nid / 6u) % 12u;
    const int b  = nid / 72u;
    const int w0 = tw * 16;
    const int h0 = th * 8;

    const int lane   = tid & 63;
    const int wv     = tid >> 6;
    const int lo     = lane & 15;
    const int hi     = lane >> 4;
    const int o_base = wv * 32;

    // A fragments of W (unchanged loads; now used as the B operand)
    bf16x8_t wfrag[2][4];
    #pragma unroll
    for (int t2 = 0; t2 < 2; ++t2)
        #pragma unroll
        for (int kc = 0; kc < 4; ++kc)
            wfrag[t2][kc] = *reinterpret_cast<const bf16x8_t*>(
                wper + (size_t)(o_base + t2 * 16 + lo) * CC + kc * 32 + hi * 8);

    // ---- staging with 4x8 register transpose (unchanged — verified) ----
    {
        const int cs4 = tid >> 3;      // 0..31: 4-channel group
        const int py  = tid & 7;
        unsigned dL[4][4], dR[4][4];
        #pragma unroll
        for (int q = 0; q < 4; ++q) {
            const unsigned short* src = xn +
                ((size_t)(b * CC + cs4 * 4 + q) * (HH * WW) + (size_t)(h0 + py) * WW + w0);
            u32x4_t L = *(const u32x4_t*)src;        // px 0..7
            u32x4_t R = *(const u32x4_t*)(src + 8);  // px 8..15
            dL[q][0]=L.x; dL[q][1]=L.y; dL[q][2]=L.z; dL[q][3]=L.w;
            dR[q][0]=R.x; dR[q][1]=R.y; dR[q][2]=R.z; dR[q][3]=R.w;
        }
        #pragma unroll
        for (int o8 = 0; o8 < 2; ++o8) {
            #pragma unroll
            for (int j = 0; j < 4; ++j) {          // pixel pair 2j, 2j+1
                const unsigned d0 = o8 ? dR[0][j] : dL[0][j];
                const unsigned d1 = o8 ? dR[1][j] : dL[1][j];
                const unsigned d2 = o8 ? dR[2][j] : dL[2][j];
                const unsigned d3 = o8 ? dR[3][j] : dL[3][j];
                u32x2_t we, wo;
                we.x = __builtin_amdgcn_perm(d1, d0, 0x05040100u);  // ch0|ch1 (even px)
                we.y = __builtin_amdgcn_perm(d3, d2, 0x05040100u);  // ch2|ch3
                wo.x = __builtin_amdgcn_perm(d1, d0, 0x07060302u);  // odd px
                wo.y = __builtin_amdgcn_perm(d3, d2, 0x07060302u);
                const int pe = py * 16 + o8 * 8 + 2 * j;
                const int po = pe + 1;
                *reinterpret_cast<u32x2_t*>(&xnb[(unsigned)pe * 256 +
                    (((unsigned)cs4 * 8) ^ (((unsigned)pe & 7u) << 4))]) = we;
                *reinterpret_cast<u32x2_t*>(&xnb[(unsigned)po * 256 +
                    (((unsigned)cs4 * 8) ^ (((unsigned)po & 7u) << 4))]) = wo;
            }
        }
    }

    __syncthreads();

    // ---- MFMA: C[row=pixel][col=o] via swapped operands ----
    f32x4_t acc[8][2];
    #pragma unroll
    for (int pt = 0; pt < 8; ++pt) {
        acc[pt][0] = (f32x4_t){0.f, 0.f, 0.f, 0.f};
        acc[pt][1] = (f32x4_t){0.f, 0.f, 0.f, 0.f};
    }

    #pragma unroll
    for (int pt = 0; pt < 8; ++pt) {
        const unsigned rowbase = (unsigned)(pt * 16 + lo) * 256;
        const unsigned sw = (unsigned)((lo & 7) << 4);
        #pragma unroll
        for (int kc = 0; kc < 4; ++kc) {
            bf16x8_t xfrag = *reinterpret_cast<const bf16x8_t*>(
                &xnb[rowbase + (((unsigned)(kc * 64 + hi * 16)) ^ sw)]);
            acc[pt][0] = __builtin_amdgcn_mfma_f32_16x16x32_bf16(
                xfrag, wfrag[0][kc], acc[pt][0], 0, 0, 0);
            acc[pt][1] = __builtin_amdgcn_mfma_f32_16x16x32_bf16(
                xfrag, wfrag[1][kc], acc[pt][1], 0, 0, 0);
        }
    }

    // ---- epilogue: per-lane o, dwordx4 stores over w ----
    float iv2[2], bs2[2];
    #pragma unroll
    for (int t2 = 0; t2 < 2; ++t2) {
        iv2[t2] = invp[o_base + t2 * 16 + lo];
        bs2[t2] = biasp[o_base + t2 * 16 + lo];
    }

    #pragma unroll
    for (int pt = 0; pt < 8; ++pt) {
        const int hrow = h0 + pt;
        #pragma unroll
        for (int t2 = 0; t2 < 2; ++t2) {
            const int o = o_base + t2 * 16 + lo;
            f32x4_t vv;
            #pragma unroll
            for (int r = 0; r < 4; ++r)
                vv[r] = fmaxf(fmaf(acc[pt][t2][r], iv2[t2], bs2[t2]), 0.f);
            *reinterpret_cast<f32x4_t*>(
                out + ((size_t)(b * CC + o) * HH + hrow) * WW + w0 + hi * 4) = vv;
        }
    }
}

// ---------------------------------------------------------------------------
// Fallback (ws too small): R5 fused kernel, known-good at ~127 us e2e.
// ---------------------------------------------------------------------------
__global__ __launch_bounds__(256, 3)
void fused_main(const float* __restrict__ x, const float* __restrict__ kk,
                const unsigned short* __restrict__ wper,
                const float* __restrict__ invp, const float* __restrict__ biasp,
                float* __restrict__ out)
{
    __shared__ __align__(16) unsigned char xnb[128 * 256];
    const int tid = threadIdx.x;
    const unsigned wg  = blockIdx.x;
    const unsigned nid = (wg & 7u) * 288u + (wg >> 3);
    const int bx = nid % 6u;
    const int by = (nid / 6u) % 12u;
    const int bb = nid / 72u;
    const int w0 = bx * 16;
    const int h0 = by * 8;
    {
        const int wq = tid & 3;
        const int cp = tid >> 2;
        const int s  = cp << 1;
        const int kc = s >> 5, rr = s & 31, gg = rr >> 3, jj = rr & 7;
        const int cA = kc * 32 + gg * 4 + (jj & 3) + 16 * (jj >> 2);
        const int gw = w0 + wq * 4;
        const bool l_edge = (gw == 0);
        const bool r_edge = (gw + 4 >= WW);
        const float* planeA = x + (size_t)(bb * CC + cA) * (HH * WW);
        float kwA[9], kwB[9];
        {
            const float* kp = kk + (size_t)(bb * CC + cA) * 9;
            f32x4u_t q0 = *(const f32x4u_t*)(kp + 0);
            f32x4u_t q1 = *(const f32x4u_t*)(kp + 4);
            f32x4u_t q2 = *(const f32x4u_t*)(kp + 8);
            f32x4u_t q3 = *(const f32x4u_t*)(kp + 12);
            float     e16 = kp[16], e17 = kp[17];
            kwA[0]=q0.x; kwA[1]=q0.y; kwA[2]=q0.z; kwA[3]=q0.w;
            kwA[4]=q1.x; kwA[5]=q1.y; kwA[6]=q1.z; kwA[7]=q1.w;
            kwA[8]=q2.x;
            kwB[0]=q2.y; kwB[1]=q2.z; kwB[2]=q2.w;
            kwB[3]=q3.x; kwB[4]=q3.y; kwB[5]=q3.z; kwB[6]=q3.w;
            kwB[7]=e16;  kwB[8]=e17;
        }
        float xd[2][10][6];
        #pragma unroll
        for (int q = 0; q < 2; ++q) {
            const float* plane = planeA + q * (HH * WW);
            #pragma unroll
            for (int r = 0; r < 10; ++r) {
                const int row = h0 - 1 + r;
                const bool valid = (row >= 0) && (row < HH);
                const int rrow = row < 0 ? 0 : (row >= HH ? HH - 1 : row);
                const float* rp = plane + rrow * WW + gw;
                f32x4_t M = *(const f32x4_t*)rp;
                float vl = rp[l_edge ? 0 : -1];
                float vr = rp[r_edge ? 3 : 4];
                xd[q][r][0] = (valid && !l_edge) ? vl : 0.f;
                xd[q][r][1] = valid ? M.x : 0.f;
                xd[q][r][2] = valid ? M.y : 0.f;
                xd[q][r][3] = valid ? M.z : 0.f;
                xd[q][r][4] = valid ? M.w : 0.f;
                xd[q][r][5] = (valid && !r_edge) ? vr : 0.f;
            }
        }
        #pragma unroll
        for (int py = 0; py < 8; ++py) {
            #pragma unroll
            for (int i = 0; i < 4; ++i) {
                float sA = 0.f, sB = 0.f;
                #pragma unroll
                for (int t = 0; t < 3; ++t) {
                    sA = fmaf(xd[0][py + 0][i + t], kwA[t],     sA);
                    sA = fmaf(xd[0][py + 1][i + t], kwA[3 + t], sA);
                    sA = fmaf(xd[0][py + 2][i + t], kwA[6 + t], sA);
                    sB = fmaf(xd[1][py + 0][i + t], kwB[t],     sB);
                    sB = fmaf(xd[1][py + 1][i + t], kwB[3 + t], sB);
                    sB = fmaf(xd[1][py + 2][i + t], kwB[6 + t], sB);
                }
                __hip_bfloat16 hA = __float2bfloat16(sA);
                __hip_bfloat16 hB = __float2bfloat16(sB);
                unsigned pk = (unsigned)*reinterpret_cast<unsigned short*>(&hA)
                            | ((unsigned)*reinterpret_cast<unsigned short*>(&hB) << 16);
                const int p = py * 16 + wq * 4 + i;
                const unsigned boff = ((unsigned)(cp << 2)) ^ (((unsigned)p & 7u) << 4);
                *reinterpret_cast<unsigned*>(&xnb[(unsigned)p * 256 + boff]) = pk;
            }
        }
    }
    __syncthreads();
    {
        const int lane   = tid & 63;
        const int wv     = tid >> 6;
        const int lo     = lane & 15;
        const int hi     = lane >> 4;
        const int o_base = wv * 32;
        bf16x8_t afrag[2][4];
        #pragma unroll
        for (int t2 = 0; t2 < 2; ++t2)
            #pragma unroll
            for (int kc = 0; kc < 4; ++kc)
                afrag[t2][kc] = *reinterpret_cast<const bf16x8_t*>(
                    wper + (size_t)(o_base + t2 * 16 + lo) * CC + kc * 32 + hi * 8);
        f32x4_t acc[8][2];
        #pragma unroll
        for (int pt = 0; pt < 8; ++pt) {
            acc[pt][0] = (f32x4_t){0.f, 0.f, 0.f, 0.f};
            acc[pt][1] = (f32x4_t){0.f, 0.f, 0.f, 0.f};
        }
        #pragma unroll
        for (int pt = 0; pt < 8; ++pt) {
            const unsigned rowbase = (unsigned)(pt * 16 + lo) * 256;
            const unsigned sw = (unsigned)((lo & 7) << 4);
            #pragma unroll
            for (int kc = 0; kc < 4; ++kc) {
                bf16x8_t bfrag = *reinterpret_cast<const bf16x8_t*>(
                    &xnb[rowbase + (((unsigned)(kc * 64 + hi * 16)) ^ sw)]);
                acc[pt][0] = __builtin_amdgcn_mfma_f32_16x16x32_bf16(
                    afrag[0][kc], bfrag, acc[pt][0], 0, 0, 0);
                acc[pt][1] = __builtin_amdgcn_mfma_f32_16x16x32_bf16(
                    afrag[1][kc], bfrag, acc[pt][1], 0, 0, 0);
            }
        }
        float iv[2][4], bs[2][4];
        #pragma unroll
        for (int t2 = 0; t2 < 2; ++t2)
            #pragma unroll
            for (int r = 0; r < 4; ++r) {
                const int o = o_base + t2 * 16 + hi * 4 + r;
                iv[t2][r] = invp[o];
                bs[t2][r] = biasp[o];
            }
        #pragma unroll
        for (int pt = 0; pt < 8; ++pt) {
            const int hrow = h0 + pt;
            #pragma unroll
            for (int t2 = 0; t2 < 2; ++t2) {
                #pragma unroll
                for (int r = 0; r < 4; ++r) {
                    const int o = o_base + t2 * 16 + hi * 4 + r;
                    float val = fmaf(acc[pt][t2][r], iv[t2][r], bs[t2][r]);
                    val = fmaxf(val, 0.f);
                    out[((size_t)(bb * CC + o) * HH + hrow) * WW + w0 + lo] = val;
                }
            }
        }
    }
}

extern "C" void kernel_launch(void* const* d_in, const int* in_sizes, int n_in,
                              void* d_out, int out_size, void* d_ws, size_t ws_size,
                              hipStream_t stream) {
    const float* x   = (const float*)d_in[0];
    const float* kk  = (const float*)d_in[1];
    const float* pwt = (const float*)d_in[2];
    const float* g   = (const float*)d_in[3];
    const float* b   = (const float*)d_in[4];
    const float* m   = (const float*)d_in[5];
    const float* v   = (const float*)d_in[6];
    float* out = (float*)d_out;

    unsigned short* wper = (unsigned short*)d_ws;                 // 32 KB
    float* inv  = (float*)((char*)d_ws + 32768);                  // 512 B
    float* bias = (float*)((char*)d_ws + 32768 + 512);            // 512 B
    unsigned short* xn = (unsigned short*)((char*)d_ws + 36864);  // 75.5 MB
    const size_t need = 36864 + (size_t)BB * CC * HH * WW * 2;

    prep_kernel<<<64, 256, 0, stream>>>(pwt, g, b, m, v, wper, inv, bias);
    if (ws_size >= need) {
        dw_kernel<<<dim3(18432), 256, 0, stream>>>(x, kk, xn);
        pw_kernel<<<dim3(2304), 256, 0, stream>>>(xn, wper, inv, bias, out);
    } else {
        fused_main<<<dim3(2304), 256, 0, stream>>>(x, kk, wper, inv, bias, out);
    }
}

// Round 9
// 127.645 us; speedup vs baseline: 1.0689x; 1.0689x over previous
//
#include <hip/hip_runtime.h>
#include <hip/hip_bf16.h>

#define BB 32
#define CC 128
#define HH 96
#define WW 96
#define BN_EPS 1e-5f

typedef __attribute__((ext_vector_type(8))) short bf16x8_t;
typedef __attribute__((ext_vector_type(4))) float f32x4_t;
typedef __attribute__((ext_vector_type(4), aligned(4))) float f32x4u_t;
typedef __attribute__((ext_vector_type(2))) unsigned int u32x2_t;
typedef __attribute__((ext_vector_type(4))) unsigned int u32x4_t;

// ---------------------------------------------------------------------------
// Prep: W fp32 -> bf16, k-permuted for mfma_f32_16x16x32_bf16 split-k frags
//   storage cidx = kc*32 + g*8 + j  <->  actual c = kc*32 + g*4 + (j&3) + 16*(j>>2)
// Also folds BN to inv/bias.   (unchanged — verified)
// ---------------------------------------------------------------------------
__global__ __launch_bounds__(256)
void prep_kernel(const float* __restrict__ pw,
                 const float* __restrict__ g, const float* __restrict__ b,
                 const float* __restrict__ m, const float* __restrict__ v,
                 unsigned short* __restrict__ wper,
                 float* __restrict__ inv, float* __restrict__ bias)
{
    int t = blockIdx.x * 256 + threadIdx.x;
    if (t < CC * CC) {
        int o = t >> 7, cidx = t & 127;
        int kc = cidx >> 5, r = cidx & 31, gg = r >> 3, j = r & 7;
        int c = kc * 32 + gg * 4 + (j & 3) + 16 * (j >> 2);
        __hip_bfloat16 h = __float2bfloat16(pw[o * CC + c]);
        wper[o * CC + cidx] = *reinterpret_cast<unsigned short*>(&h);
    }
    if (t < CC) {
        float iv = g[t] * rsqrtf(v[t] + BN_EPS);
        inv[t] = iv;
        bias[t] = b[t] - m[t] * iv;
    }
}

// ---------------------------------------------------------------------------
// Kernel A (R9): depthwise 3x3, 8 OUTPUT ROWS per thread via 3-row register
// sliding window. Reads 10 rows per 8 (h-halo 1.25x, was 3x) -> L1 traffic
// 2.4x lower; 40 VMEM per 64 outputs (was 12 per 8). ~60 live VGPR, no MFMA
// pressure -> (256,6). Block order (b,th)-slab-major so the pw XCD chunks
// see locally-written xn.
// ---------------------------------------------------------------------------
__global__ __launch_bounds__(256, 6)
void dw_kernel(const float* __restrict__ x, const float* __restrict__ kk,
               unsigned short* __restrict__ xn)
{
    const int u = blockIdx.x * 256 + threadIdx.x;  // ((b*12+th)*128+cs)*12+woct
    const int woct = u % 12;
    int t1 = u / 12;
    const int cs = t1 & 127;
    int t2 = t1 >> 7;
    const int th = t2 % 12;
    const int b  = t2 / 12;

    // storage -> actual channel permutation
    const int kc = cs >> 5, rr = cs & 31, gg = rr >> 3, jj = rr & 7;
    const int c = kc * 32 + gg * 4 + (jj & 3) + 16 * (jj >> 2);

    const int w0 = woct * 8;
    const int h0 = th * 8;
    const bool l_edge = (w0 == 0);
    const bool r_edge = (w0 + 8 >= WW);

    const float* plane = x + (size_t)(b * CC + c) * (HH * WW);

    float kw[9];
    {
        const float* kp = kk + (size_t)(b * CC + c) * 9;
        f32x4u_t q0 = *(const f32x4u_t*)(kp);
        f32x4u_t q1 = *(const f32x4u_t*)(kp + 4);
        kw[0]=q0.x; kw[1]=q0.y; kw[2]=q0.z; kw[3]=q0.w;
        kw[4]=q1.x; kw[5]=q1.y; kw[6]=q1.z; kw[7]=q1.w;
        kw[8]=kp[8];
    }

    float rA[10], rB[10], rC[10];
    auto load_row = [&](int row, float* o) {
        const bool valid = (row >= 0) && (row < HH);
        const int rrow = row < 0 ? 0 : (row >= HH ? HH - 1 : row);
        const float* rp = plane + rrow * WW + w0;   // 32B aligned
        f32x4_t M0 = *(const f32x4_t*)rp;
        f32x4_t M1 = *(const f32x4_t*)(rp + 4);
        float vl = rp[l_edge ? 0 : -1];
        float vr = rp[r_edge ? 7 : 8];
        o[0] = (valid && !l_edge) ? vl : 0.f;
        o[1] = valid ? M0.x : 0.f;
        o[2] = valid ? M0.y : 0.f;
        o[3] = valid ? M0.z : 0.f;
        o[4] = valid ? M0.w : 0.f;
        o[5] = valid ? M1.x : 0.f;
        o[6] = valid ? M1.y : 0.f;
        o[7] = valid ? M1.z : 0.f;
        o[8] = valid ? M1.w : 0.f;
        o[9] = (valid && !r_edge) ? vr : 0.f;
    };

    load_row(h0 - 1, rA);
    load_row(h0,     rB);

    unsigned short* dst0 = xn + ((size_t)(b * CC + cs) * (HH * WW) + (size_t)h0 * WW + w0);

    #pragma unroll
    for (int py = 0; py < 8; ++py) {
        load_row(h0 + py + 1, rC);

        unsigned pkw[4];
        #pragma unroll
        for (int i = 0; i < 4; ++i) {
            float s0 = 0.f, s1 = 0.f;
            #pragma unroll
            for (int t = 0; t < 3; ++t) {
                s0 = fmaf(rA[2 * i + t],     kw[t],     s0);
                s0 = fmaf(rB[2 * i + t],     kw[3 + t], s0);
                s0 = fmaf(rC[2 * i + t],     kw[6 + t], s0);
                s1 = fmaf(rA[2 * i + 1 + t], kw[t],     s1);
                s1 = fmaf(rB[2 * i + 1 + t], kw[3 + t], s1);
                s1 = fmaf(rC[2 * i + 1 + t], kw[6 + t], s1);
            }
            __hip_bfloat16 h0b = __float2bfloat16(s0);
            __hip_bfloat16 h1b = __float2bfloat16(s1);
            pkw[i] = (unsigned)*reinterpret_cast<unsigned short*>(&h0b)
                   | ((unsigned)*reinterpret_cast<unsigned short*>(&h1b) << 16);
        }
        u32x4_t pk;
        pk.x = pkw[0]; pk.y = pkw[1]; pk.z = pkw[2]; pk.w = pkw[3];
        *reinterpret_cast<u32x4_t*>(dst0 + (size_t)py * WW) = pk;   // 16B store

        #pragma unroll
        for (int t = 0; t < 10; ++t) { rA[t] = rB[t]; rB[t] = rC[t]; }
    }
}

// ---------------------------------------------------------------------------
// Kernel B: pointwise MFMA GEMM + BN + ReLU (R8 — swap + vector stores,
// numerically verified: absmax unchanged).
// ---------------------------------------------------------------------------
__global__ __launch_bounds__(256, 4)
void pw_kernel(const unsigned short* __restrict__ xn,
               const unsigned short* __restrict__ wper,
               const float* __restrict__ invp, const float* __restrict__ biasp,
               float* __restrict__ out)
{
    __shared__ __align__(16) unsigned char xnb[128 * 256];
    const int tid = threadIdx.x;

    // chunked XCD swizzle (2304 = 8 x 288)
    const unsigned wg  = blockIdx.x;
    const unsigned nid = (wg & 7u) * 288u + (wg >> 3);
    const int tw = nid % 6u;
    const int th = (nid / 6u) % 12u;
    const int b  = nid / 72u;
    const int w0 = tw * 16;
    const int h0 = th * 8;

    const int lane   = tid & 63;
    const int wv     = tid >> 6;
    const int lo     = lane & 15;
    const int hi     = lane >> 4;
    const int o_base = wv * 32;

    bf16x8_t wfrag[2][4];
    #pragma unroll
    for (int t2 = 0; t2 < 2; ++t2)
        #pragma unroll
        for (int kc = 0; kc < 4; ++kc)
            wfrag[t2][kc] = *reinterpret_cast<const bf16x8_t*>(
                wper + (size_t)(o_base + t2 * 16 + lo) * CC + kc * 32 + hi * 8);

    // ---- staging with 4x8 register transpose (verified) ----
    {
        const int cs4 = tid >> 3;      // 0..31: 4-channel group
        const int py  = tid & 7;
        unsigned dL[4][4], dR[4][4];
        #pragma unroll
        for (int q = 0; q < 4; ++q) {
            const unsigned short* src = xn +
                ((size_t)(b * CC + cs4 * 4 + q) * (HH * WW) + (size_t)(h0 + py) * WW + w0);
            u32x4_t L = *(const u32x4_t*)src;        // px 0..7
            u32x4_t R = *(const u32x4_t*)(src + 8);  // px 8..15
            dL[q][0]=L.x; dL[q][1]=L.y; dL[q][2]=L.z; dL[q][3]=L.w;
            dR[q][0]=R.x; dR[q][1]=R.y; dR[q][2]=R.z; dR[q][3]=R.w;
        }
        #pragma unroll
        for (int o8 = 0; o8 < 2; ++o8) {
            #pragma unroll
            for (int j = 0; j < 4; ++j) {          // pixel pair 2j, 2j+1
                const unsigned d0 = o8 ? dR[0][j] : dL[0][j];
                const unsigned d1 = o8 ? dR[1][j] : dL[1][j];
                const unsigned d2 = o8 ? dR[2][j] : dL[2][j];
                const unsigned d3 = o8 ? dR[3][j] : dL[3][j];
                u32x2_t we, wo;
                we.x = __builtin_amdgcn_perm(d1, d0, 0x05040100u);
                we.y = __builtin_amdgcn_perm(d3, d2, 0x05040100u);
                wo.x = __builtin_amdgcn_perm(d1, d0, 0x07060302u);
                wo.y = __builtin_amdgcn_perm(d3, d2, 0x07060302u);
                const int pe = py * 16 + o8 * 8 + 2 * j;
                const int po = pe + 1;
                *reinterpret_cast<u32x2_t*>(&xnb[(unsigned)pe * 256 +
                    (((unsigned)cs4 * 8) ^ (((unsigned)pe & 7u) << 4))]) = we;
                *reinterpret_cast<u32x2_t*>(&xnb[(unsigned)po * 256 +
                    (((unsigned)cs4 * 8) ^ (((unsigned)po & 7u) << 4))]) = wo;
            }
        }
    }

    __syncthreads();

    // ---- MFMA: C[row=pixel][col=o] via swapped operands (verified) ----
    f32x4_t acc[8][2];
    #pragma unroll
    for (int pt = 0; pt < 8; ++pt) {
        acc[pt][0] = (f32x4_t){0.f, 0.f, 0.f, 0.f};
        acc[pt][1] = (f32x4_t){0.f, 0.f, 0.f, 0.f};
    }

    #pragma unroll
    for (int pt = 0; pt < 8; ++pt) {
        const unsigned rowbase = (unsigned)(pt * 16 + lo) * 256;
        const unsigned sw = (unsigned)((lo & 7) << 4);
        #pragma unroll
        for (int kc = 0; kc < 4; ++kc) {
            bf16x8_t xfrag = *reinterpret_cast<const bf16x8_t*>(
                &xnb[rowbase + (((unsigned)(kc * 64 + hi * 16)) ^ sw)]);
            acc[pt][0] = __builtin_amdgcn_mfma_f32_16x16x32_bf16(
                xfrag, wfrag[0][kc], acc[pt][0], 0, 0, 0);
            acc[pt][1] = __builtin_amdgcn_mfma_f32_16x16x32_bf16(
                xfrag, wfrag[1][kc], acc[pt][1], 0, 0, 0);
        }
    }

    // ---- epilogue: per-lane o, dwordx4 stores over w ----
    float iv2[2], bs2[2];
    #pragma unroll
    for (int t2 = 0; t2 < 2; ++t2) {
        iv2[t2] = invp[o_base + t2 * 16 + lo];
        bs2[t2] = biasp[o_base + t2 * 16 + lo];
    }

    #pragma unroll
    for (int pt = 0; pt < 8; ++pt) {
        const int hrow = h0 + pt;
        #pragma unroll
        for (int t2 = 0; t2 < 2; ++t2) {
            const int o = o_base + t2 * 16 + lo;
            f32x4_t vv;
            #pragma unroll
            for (int r = 0; r < 4; ++r)
                vv[r] = fmaxf(fmaf(acc[pt][t2][r], iv2[t2], bs2[t2]), 0.f);
            *reinterpret_cast<f32x4_t*>(
                out + ((size_t)(b * CC + o) * HH + hrow) * WW + w0 + hi * 4) = vv;
        }
    }
}

// ---------------------------------------------------------------------------
// Fallback (ws too small): R5 fused kernel.
// ---------------------------------------------------------------------------
__global__ __launch_bounds__(256, 3)
void fused_main(const float* __restrict__ x, const float* __restrict__ kk,
                const unsigned short* __restrict__ wper,
                const float* __restrict__ invp, const float* __restrict__ biasp,
                float* __restrict__ out)
{
    __shared__ __align__(16) unsigned char xnb[128 * 256];
    const int tid = threadIdx.x;
    const unsigned wg  = blockIdx.x;
    const unsigned nid = (wg & 7u) * 288u + (wg >> 3);
    const int bx = nid % 6u;
    const int by = (nid / 6u) % 12u;
    const int bb = nid / 72u;
    const int w0 = bx * 16;
    const int h0 = by * 8;
    {
        const int wq = tid & 3;
        const int cp = tid >> 2;
        const int s  = cp << 1;
        const int kc = s >> 5, rr = s & 31, gg = rr >> 3, jj = rr & 7;
        const int cA = kc * 32 + gg * 4 + (jj & 3) + 16 * (jj >> 2);
        const int gw = w0 + wq * 4;
        const bool l_edge = (gw == 0);
        const bool r_edge = (gw + 4 >= WW);
        const float* planeA = x + (size_t)(bb * CC + cA) * (HH * WW);
        float kwA[9], kwB[9];
        {
            const float* kp = kk + (size_t)(bb * CC + cA) * 9;
            f32x4u_t q0 = *(const f32x4u_t*)(kp + 0);
            f32x4u_t q1 = *(const f32x4u_t*)(kp + 4);
            f32x4u_t q2 = *(const f32x4u_t*)(kp + 8);
            f32x4u_t q3 = *(const f32x4u_t*)(kp + 12);
            float     e16 = kp[16], e17 = kp[17];
            kwA[0]=q0.x; kwA[1]=q0.y; kwA[2]=q0.z; kwA[3]=q0.w;
            kwA[4]=q1.x; kwA[5]=q1.y; kwA[6]=q1.z; kwA[7]=q1.w;
            kwA[8]=q2.x;
            kwB[0]=q2.y; kwB[1]=q2.z; kwB[2]=q2.w;
            kwB[3]=q3.x; kwB[4]=q3.y; kwB[5]=q3.z; kwB[6]=q3.w;
            kwB[7]=e16;  kwB[8]=e17;
        }
        float xd[2][10][6];
        #pragma unroll
        for (int q = 0; q < 2; ++q) {
            const float* plane = planeA + q * (HH * WW);
            #pragma unroll
            for (int r = 0; r < 10; ++r) {
                const int row = h0 - 1 + r;
                const bool valid = (row >= 0) && (row < HH);
                const int rrow = row < 0 ? 0 : (row >= HH ? HH - 1 : row);
                const float* rp = plane + rrow * WW + gw;
                f32x4_t M = *(const f32x4_t*)rp;
                float vl = rp[l_edge ? 0 : -1];
                float vr = rp[r_edge ? 3 : 4];
                xd[q][r][0] = (valid && !l_edge) ? vl : 0.f;
                xd[q][r][1] = valid ? M.x : 0.f;
                xd[q][r][2] = valid ? M.y : 0.f;
                xd[q][r][3] = valid ? M.z : 0.f;
                xd[q][r][4] = valid ? M.w : 0.f;
                xd[q][r][5] = (valid && !r_edge) ? vr : 0.f;
            }
        }
        #pragma unroll
        for (int py = 0; py < 8; ++py) {
            #pragma unroll
            for (int i = 0; i < 4; ++i) {
                float sA = 0.f, sB = 0.f;
                #pragma unroll
                for (int t = 0; t < 3; ++t) {
                    sA = fmaf(xd[0][py + 0][i + t], kwA[t],     sA);
                    sA = fmaf(xd[0][py + 1][i + t], kwA[3 + t], sA);
                    sA = fmaf(xd[0][py + 2][i + t], kwA[6 + t], sA);
                    sB = fmaf(xd[1][py + 0][i + t], kwB[t],     sB);
                    sB = fmaf(xd[1][py + 1][i + t], kwB[3 + t], sB);
                    sB = fmaf(xd[1][py + 2][i + t], kwB[6 + t], sB);
                }
                __hip_bfloat16 hA = __float2bfloat16(sA);
                __hip_bfloat16 hB = __float2bfloat16(sB);
                unsigned pk = (unsigned)*reinterpret_cast<unsigned short*>(&hA)
                            | ((unsigned)*reinterpret_cast<unsigned short*>(&hB) << 16);
                const int p = py * 16 + wq * 4 + i;
                const unsigned boff = ((unsigned)(cp << 2)) ^ (((unsigned)p & 7u) << 4);
                *reinterpret_cast<unsigned*>(&xnb[(unsigned)p * 256 + boff]) = pk;
            }
        }
    }
    __syncthreads();
    {
        const int lane   = tid & 63;
        const int wv     = tid >> 6;
        const int lo     = lane & 15;
        const int hi     = lane >> 4;
        const int o_base = wv * 32;
        bf16x8_t afrag[2][4];
        #pragma unroll
        for (int t2 = 0; t2 < 2; ++t2)
            #pragma unroll
            for (int kc = 0; kc < 4; ++kc)
                afrag[t2][kc] = *reinterpret_cast<const bf16x8_t*>(
                    wper + (size_t)(o_base + t2 * 16 + lo) * CC + kc * 32 + hi * 8);
        f32x4_t acc[8][2];
        #pragma unroll
        for (int pt = 0; pt < 8; ++pt) {
            acc[pt][0] = (f32x4_t){0.f, 0.f, 0.f, 0.f};
            acc[pt][1] = (f32x4_t){0.f, 0.f, 0.f, 0.f};
        }
        #pragma unroll
        for (int pt = 0; pt < 8; ++pt) {
            const unsigned rowbase = (unsigned)(pt * 16 + lo) * 256;
            const unsigned sw = (unsigned)((lo & 7) << 4);
            #pragma unroll
            for (int kc = 0; kc < 4; ++kc) {
                bf16x8_t bfrag = *reinterpret_cast<const bf16x8_t*>(
                    &xnb[rowbase + (((unsigned)(kc * 64 + hi * 16)) ^ sw)]);
                acc[pt][0] = __builtin_amdgcn_mfma_f32_16x16x32_bf16(
                    afrag[0][kc], bfrag, acc[pt][0], 0, 0, 0);
                acc[pt][1] = __builtin_amdgcn_mfma_f32_16x16x32_bf16(
                    afrag[1][kc], bfrag, acc[pt][1], 0, 0, 0);
            }
        }
        float iv[2][4], bs[2][4];
        #pragma unroll
        for (int t2 = 0; t2 < 2; ++t2)
            #pragma unroll
            for (int r = 0; r < 4; ++r) {
                const int o = o_base + t2 * 16 + hi * 4 + r;
                iv[t2][r] = invp[o];
                bs[t2][r] = biasp[o];
            }
        #pragma unroll
        for (int pt = 0; pt < 8; ++pt) {
            const int hrow = h0 + pt;
            #pragma unroll
            for (int t2 = 0; t2 < 2; ++t2) {
                #pragma unroll
                for (int r = 0; r < 4; ++r) {
                    const int o = o_base + t2 * 16 + hi * 4 + r;
                    float val = fmaf(acc[pt][t2][r], iv[t2][r], bs[t2][r]);
                    val = fmaxf(val, 0.f);
                    out[((size_t)(bb * CC + o) * HH + hrow) * WW + w0 + lo] = val;
                }
            }
        }
    }
}

extern "C" void kernel_launch(void* const* d_in, const int* in_sizes, int n_in,
                              void* d_out, int out_size, void* d_ws, size_t ws_size,
                              hipStream_t stream) {
    const float* x   = (const float*)d_in[0];
    const float* kk  = (const float*)d_in[1];
    const float* pwt = (const float*)d_in[2];
    const float* g   = (const float*)d_in[3];
    const float* b   = (const float*)d_in[4];
    const float* m   = (const float*)d_in[5];
    const float* v   = (const float*)d_in[6];
    float* out = (float*)d_out;

    unsigned short* wper = (unsigned short*)d_ws;                 // 32 KB
    float* inv  = (float*)((char*)d_ws + 32768);                  // 512 B
    float* bias = (float*)((char*)d_ws + 32768 + 512);            // 512 B
    unsigned short* xn = (unsigned short*)((char*)d_ws + 36864);  // 75.5 MB
    const size_t need = 36864 + (size_t)BB * CC * HH * WW * 2;

    prep_kernel<<<64, 256, 0, stream>>>(pwt, g, b, m, v, wper, inv, bias);
    if (ws_size >= need) {
        dw_kernel<<<dim3(2304), 256, 0, stream>>>(x, kk, xn);
        pw_kernel<<<dim3(2304), 256, 0, stream>>>(xn, wper, inv, bias, out);
    } else {
        fused_main<<<dim3(2304), 256, 0, stream>>>(x, kk, wper, inv, bias, out);
    }
}

// Round 12
// 125.064 us; speedup vs baseline: 1.0910x; 1.0206x over previous
//
#include <hip/hip_runtime.h>
#include <hip/hip_bf16.h>

#define BB 32
#define CC 128
#define HH 96
#define WW 96
#define BN_EPS 1e-5f

typedef __attribute__((ext_vector_type(8))) short bf16x8_t;
typedef __attribute__((ext_vector_type(4))) float f32x4_t;
typedef __attribute__((ext_vector_type(4), aligned(4))) float f32x4u_t;
typedef __attribute__((ext_vector_type(2))) unsigned int u32x2_t;
typedef __attribute__((ext_vector_type(4))) unsigned int u32x4_t;

// ---------------------------------------------------------------------------
// Prep: W fp32 -> bf16, k-permuted for mfma_f32_16x16x32_bf16 split-k frags
//   storage cidx = kc*32 + g*8 + j  <->  actual c = kc*32 + g*4 + (j&3) + 16*(j>>2)
// Also folds BN to inv/bias.   (unchanged — verified)
// ---------------------------------------------------------------------------
__global__ __launch_bounds__(256)
void prep_kernel(const float* __restrict__ pw,
                 const float* __restrict__ g, const float* __restrict__ b,
                 const float* __restrict__ m, const float* __restrict__ v,
                 unsigned short* __restrict__ wper,
                 float* __restrict__ inv, float* __restrict__ bias)
{
    int t = blockIdx.x * 256 + threadIdx.x;
    if (t < CC * CC) {
        int o = t >> 7, cidx = t & 127;
        int kc = cidx >> 5, r = cidx & 31, gg = r >> 3, j = r & 7;
        int c = kc * 32 + gg * 4 + (j & 3) + 16 * (j >> 2);
        __hip_bfloat16 h = __float2bfloat16(pw[o * CC + c]);
        wper[o * CC + cidx] = *reinterpret_cast<unsigned short*>(&h);
    }
    if (t < CC) {
        float iv = g[t] * rsqrtf(v[t] + BN_EPS);
        inv[t] = iv;
        bias[t] = b[t] - m[t] * iv;
    }
}

// ---------------------------------------------------------------------------
// Kernel A (R12): depthwise 3x3, 8 output rows/thread, 3-row sliding window.
// Halos via __shfl from neighbor lanes (u is tid-consecutive so lane+-1 ==
// adjacent woct), EXCEPT at the two wave-boundary lanes (64 % 12 != 0, so a
// wave edge can fall mid-image — R11's bug): lane 0 / lane 63 patch their
// halo with a predicated 1-lane scalar load. Image edges masked as before.
// Request theory: 2 vector + 2 one-lane loads per row vs R9's 2 vector +
// 2 full-wave gathers — ~2x less L1/TA request work.
// ---------------------------------------------------------------------------
__global__ __launch_bounds__(256, 6)
void dw_kernel(const float* __restrict__ x, const float* __restrict__ kk,
               unsigned short* __restrict__ xn)
{
    const int u = blockIdx.x * 256 + threadIdx.x;  // ((b*12+th)*128+cs)*12+woct
    const int lane = threadIdx.x & 63;
    const int woct = u % 12;
    int t1 = u / 12;
    const int cs = t1 & 127;
    int t2 = t1 >> 7;
    const int th = t2 % 12;
    const int b  = t2 / 12;

    // storage -> actual channel permutation
    const int kc = cs >> 5, rr = cs & 31, gg = rr >> 3, jj = rr & 7;
    const int c = kc * 32 + gg * 4 + (jj & 3) + 16 * (jj >> 2);

    const int w0 = woct * 8;
    const int h0 = th * 8;
    const bool l_edge = (woct == 0);
    const bool r_edge = (woct == 11);

    const float* plane = x + (size_t)(b * CC + c) * (HH * WW);

    float kw[9];
    {
        const float* kp = kk + (size_t)(b * CC + c) * 9;
        f32x4u_t q0 = *(const f32x4u_t*)(kp);
        f32x4u_t q1 = *(const f32x4u_t*)(kp + 4);
        kw[0]=q0.x; kw[1]=q0.y; kw[2]=q0.z; kw[3]=q0.w;
        kw[4]=q1.x; kw[5]=q1.y; kw[6]=q1.z; kw[7]=q1.w;
        kw[8]=kp[8];
    }

    float rA[10], rB[10], rC[10];
    auto load_row = [&](int row, float* o) {
        const bool valid = (row >= 0) && (row < HH);
        const int rrow = row < 0 ? 0 : (row >= HH ? HH - 1 : row);
        const float* rp = plane + rrow * WW + w0;   // 32B aligned
        f32x4_t M0 = *(const f32x4_t*)rp;
        f32x4_t M1 = *(const f32x4_t*)(rp + 4);
        // halos from neighbor lanes (u is consecutive across the whole block)
        float vl = __shfl_up(M1.w, 1);              // lane-1's px7 = x[w0-1]
        float vr = __shfl_down(M0.x, 1);            // lane+1's px0 = x[w0+8]
        // wave-boundary patch (R11 bug fix): lane 0/63 have no valid neighbor
        if (lane == 0  && !l_edge) vl = rp[-1];
        if (lane == 63 && !r_edge) vr = rp[8];
        o[0] = (valid && !l_edge) ? vl : 0.f;
        o[1] = valid ? M0.x : 0.f;
        o[2] = valid ? M0.y : 0.f;
        o[3] = valid ? M0.z : 0.f;
        o[4] = valid ? M0.w : 0.f;
        o[5] = valid ? M1.x : 0.f;
        o[6] = valid ? M1.y : 0.f;
        o[7] = valid ? M1.z : 0.f;
        o[8] = valid ? M1.w : 0.f;
        o[9] = (valid && !r_edge) ? vr : 0.f;
    };

    load_row(h0 - 1, rA);
    load_row(h0,     rB);

    unsigned short* dst0 = xn + ((size_t)(b * CC + cs) * (HH * WW) + (size_t)h0 * WW + w0);

    #pragma unroll
    for (int py = 0; py < 8; ++py) {
        load_row(h0 + py + 1, rC);

        unsigned pkw[4];
        #pragma unroll
        for (int i = 0; i < 4; ++i) {
            float s0 = 0.f, s1 = 0.f;
            #pragma unroll
            for (int t = 0; t < 3; ++t) {
                s0 = fmaf(rA[2 * i + t],     kw[t],     s0);
                s0 = fmaf(rB[2 * i + t],     kw[3 + t], s0);
                s0 = fmaf(rC[2 * i + t],     kw[6 + t], s0);
                s1 = fmaf(rA[2 * i + 1 + t], kw[t],     s1);
                s1 = fmaf(rB[2 * i + 1 + t], kw[3 + t], s1);
                s1 = fmaf(rC[2 * i + 1 + t], kw[6 + t], s1);
            }
            __hip_bfloat16 h0b = __float2bfloat16(s0);
            __hip_bfloat16 h1b = __float2bfloat16(s1);
            pkw[i] = (unsigned)*reinterpret_cast<unsigned short*>(&h0b)
                   | ((unsigned)*reinterpret_cast<unsigned short*>(&h1b) << 16);
        }
        u32x4_t pk;
        pk.x = pkw[0]; pk.y = pkw[1]; pk.z = pkw[2]; pk.w = pkw[3];
        *reinterpret_cast<u32x4_t*>(dst0 + (size_t)py * WW) = pk;   // 16B store

        #pragma unroll
        for (int t = 0; t < 10; ++t) { rA[t] = rB[t]; rB[t] = rC[t]; }
    }
}

// ---------------------------------------------------------------------------
// Kernel B: pointwise MFMA GEMM + BN + ReLU (R8/R9 — verified).
// ---------------------------------------------------------------------------
__global__ __launch_bounds__(256, 4)
void pw_kernel(const unsigned short* __restrict__ xn,
               const unsigned short* __restrict__ wper,
               const float* __restrict__ invp, const float* __restrict__ biasp,
               float* __restrict__ out)
{
    __shared__ __align__(16) unsigned char xnb[128 * 256];
    const int tid = threadIdx.x;

    // chunked XCD swizzle (2304 = 8 x 288)
    const unsigned wg  = blockIdx.x;
    const unsigned nid = (wg & 7u) * 288u + (wg >> 3);
    const int tw = nid % 6u;
    const int th = (nid / 6u) % 12u;
    const int b  = nid / 72u;
    const int w0 = tw * 16;
    const int h0 = th * 8;

    const int lane   = tid & 63;
    const int wv     = tid >> 6;
    const int lo     = lane & 15;
    const int hi     = lane >> 4;
    const int o_base = wv * 32;

    bf16x8_t wfrag[2][4];
    #pragma unroll
    for (int t2 = 0; t2 < 2; ++t2)
        #pragma unroll
        for (int kc = 0; kc < 4; ++kc)
            wfrag[t2][kc] = *reinterpret_cast<const bf16x8_t*>(
                wper + (size_t)(o_base + t2 * 16 + lo) * CC + kc * 32 + hi * 8);

    // ---- staging with 4x8 register transpose (verified) ----
    {
        const int cs4 = tid >> 3;      // 0..31: 4-channel group
        const int py  = tid & 7;
        unsigned dL[4][4], dR[4][4];
        #pragma unroll
        for (int q = 0; q < 4; ++q) {
            const unsigned short* src = xn +
                ((size_t)(b * CC + cs4 * 4 + q) * (HH * WW) + (size_t)(h0 + py) * WW + w0);
            u32x4_t L = *(const u32x4_t*)src;        // px 0..7
            u32x4_t R = *(const u32x4_t*)(src + 8);  // px 8..15
            dL[q][0]=L.x; dL[q][1]=L.y; dL[q][2]=L.z; dL[q][3]=L.w;
            dR[q][0]=R.x; dR[q][1]=R.y; dR[q][2]=R.z; dR[q][3]=R.w;
        }
        #pragma unroll
        for (int o8 = 0; o8 < 2; ++o8) {
            #pragma unroll
            for (int j = 0; j < 4; ++j) {          // pixel pair 2j, 2j+1
                const unsigned d0 = o8 ? dR[0][j] : dL[0][j];
                const unsigned d1 = o8 ? dR[1][j] : dL[1][j];
                const unsigned d2 = o8 ? dR[2][j] : dL[2][j];
                const unsigned d3 = o8 ? dR[3][j] : dL[3][j];
                u32x2_t we, wo;
                we.x = __builtin_amdgcn_perm(d1, d0, 0x05040100u);
                we.y = __builtin_amdgcn_perm(d3, d2, 0x05040100u);
                wo.x = __builtin_amdgcn_perm(d1, d0, 0x07060302u);
                wo.y = __builtin_amdgcn_perm(d3, d2, 0x07060302u);
                const int pe = py * 16 + o8 * 8 + 2 * j;
                const int po = pe + 1;
                *reinterpret_cast<u32x2_t*>(&xnb[(unsigned)pe * 256 +
                    (((unsigned)cs4 * 8) ^ (((unsigned)pe & 7u) << 4))]) = we;
                *reinterpret_cast<u32x2_t*>(&xnb[(unsigned)po * 256 +
                    (((unsigned)cs4 * 8) ^ (((unsigned)po & 7u) << 4))]) = wo;
            }
        }
    }

    __syncthreads();

    // ---- MFMA: C[row=pixel][col=o] via swapped operands (verified) ----
    f32x4_t acc[8][2];
    #pragma unroll
    for (int pt = 0; pt < 8; ++pt) {
        acc[pt][0] = (f32x4_t){0.f, 0.f, 0.f, 0.f};
        acc[pt][1] = (f32x4_t){0.f, 0.f, 0.f, 0.f};
    }

    #pragma unroll
    for (int pt = 0; pt < 8; ++pt) {
        const unsigned rowbase = (unsigned)(pt * 16 + lo) * 256;
        const unsigned sw = (unsigned)((lo & 7) << 4);
        #pragma unroll
        for (int kc = 0; kc < 4; ++kc) {
            bf16x8_t xfrag = *reinterpret_cast<const bf16x8_t*>(
                &xnb[rowbase + (((unsigned)(kc * 64 + hi * 16)) ^ sw)]);
            acc[pt][0] = __builtin_amdgcn_mfma_f32_16x16x32_bf16(
                xfrag, wfrag[0][kc], acc[pt][0], 0, 0, 0);
            acc[pt][1] = __builtin_amdgcn_mfma_f32_16x16x32_bf16(
                xfrag, wfrag[1][kc], acc[pt][1], 0, 0, 0);
        }
    }

    // ---- epilogue: per-lane o, dwordx4 stores over w ----
    float iv2[2], bs2[2];
    #pragma unroll
    for (int t2 = 0; t2 < 2; ++t2) {
        iv2[t2] = invp[o_base + t2 * 16 + lo];
        bs2[t2] = biasp[o_base + t2 * 16 + lo];
    }

    #pragma unroll
    for (int pt = 0; pt < 8; ++pt) {
        const int hrow = h0 + pt;
        #pragma unroll
        for (int t2 = 0; t2 < 2; ++t2) {
            const int o = o_base + t2 * 16 + lo;
            f32x4_t vv;
            #pragma unroll
            for (int r = 0; r < 4; ++r)
                vv[r] = fmaxf(fmaf(acc[pt][t2][r], iv2[t2], bs2[t2]), 0.f);
            *reinterpret_cast<f32x4_t*>(
                out + ((size_t)(b * CC + o) * HH + hrow) * WW + w0 + hi * 4) = vv;
        }
    }
}

// ---------------------------------------------------------------------------
// Fallback (ws too small): R5 fused kernel.
// ---------------------------------------------------------------------------
__global__ __launch_bounds__(256, 3)
void fused_main(const float* __restrict__ x, const float* __restrict__ kk,
                const unsigned short* __restrict__ wper,
                const float* __restrict__ invp, const float* __restrict__ biasp,
                float* __restrict__ out)
{
    __shared__ __align__(16) unsigned char xnb[128 * 256];
    const int tid = threadIdx.x;
    const unsigned wg  = blockIdx.x;
    const unsigned nid = (wg & 7u) * 288u + (wg >> 3);
    const int bx = nid % 6u;
    const int by = (nid / 6u) % 12u;
    const int bb = nid / 72u;
    const int w0 = bx * 16;
    const int h0 = by * 8;
    {
        const int wq = tid & 3;
        const int cp = tid >> 2;
        const int s  = cp << 1;
        const int kc = s >> 5, rr = s & 31, gg = rr >> 3, jj = rr & 7;
        const int cA = kc * 32 + gg * 4 + (jj & 3) + 16 * (jj >> 2);
        const int gw = w0 + wq * 4;
        const bool l_edge = (gw == 0);
        const bool r_edge = (gw + 4 >= WW);
        const float* planeA = x + (size_t)(bb * CC + cA) * (HH * WW);
        float kwA[9], kwB[9];
        {
            const float* kp = kk + (size_t)(bb * CC + cA) * 9;
            f32x4u_t q0 = *(const f32x4u_t*)(kp + 0);
            f32x4u_t q1 = *(const f32x4u_t*)(kp + 4);
            f32x4u_t q2 = *(const f32x4u_t*)(kp + 8);
            f32x4u_t q3 = *(const f32x4u_t*)(kp + 12);
            float     e16 = kp[16], e17 = kp[17];
            kwA[0]=q0.x; kwA[1]=q0.y; kwA[2]=q0.z; kwA[3]=q0.w;
            kwA[4]=q1.x; kwA[5]=q1.y; kwA[6]=q1.z; kwA[7]=q1.w;
            kwA[8]=q2.x;
            kwB[0]=q2.y; kwB[1]=q2.z; kwB[2]=q2.w;
            kwB[3]=q3.x; kwB[4]=q3.y; kwB[5]=q3.z; kwB[6]=q3.w;
            kwB[7]=e16;  kwB[8]=e17;
        }
        float xd[2][10][6];
        #pragma unroll
        for (int q = 0; q < 2; ++q) {
            const float* plane = planeA + q * (HH * WW);
            #pragma unroll
            for (int r = 0; r < 10; ++r) {
                const int row = h0 - 1 + r;
                const bool valid = (row >= 0) && (row < HH);
                const int rrow = row < 0 ? 0 : (row >= HH ? HH - 1 : row);
                const float* rp = plane + rrow * WW + gw;
                f32x4_t M = *(const f32x4_t*)rp;
                float vl = rp[l_edge ? 0 : -1];
                float vr = rp[r_edge ? 3 : 4];
                xd[q][r][0] = (valid && !l_edge) ? vl : 0.f;
                xd[q][r][1] = valid ? M.x : 0.f;
                xd[q][r][2] = valid ? M.y : 0.f;
                xd[q][r][3] = valid ? M.z : 0.f;
                xd[q][r][4] = valid ? M.w : 0.f;
                xd[q][r][5] = (valid && !r_edge) ? vr : 0.f;
            }
        }
        #pragma unroll
        for (int py = 0; py < 8; ++py) {
            #pragma unroll
            for (int i = 0; i < 4; ++i) {
                float sA = 0.f, sB = 0.f;
                #pragma unroll
                for (int t = 0; t < 3; ++t) {
                    sA = fmaf(xd[0][py + 0][i + t], kwA[t],     sA);
                    sA = fmaf(xd[0][py + 1][i + t], kwA[3 + t], sA);
                    sA = fmaf(xd[0][py + 2][i + t], kwA[6 + t], sA);
                    sB = fmaf(xd[1][py + 0][i + t], kwB[t],     sB);
                    sB = fmaf(xd[1][py + 1][i + t], kwB[3 + t], sB);
                    sB = fmaf(xd[1][py + 2][i + t], kwB[6 + t], sB);
                }
                __hip_bfloat16 hA = __float2bfloat16(sA);
                __hip_bfloat16 hB = __float2bfloat16(sB);
                unsigned pk = (unsigned)*reinterpret_cast<unsigned short*>(&hA)
                            | ((unsigned)*reinterpret_cast<unsigned short*>(&hB) << 16);
                const int p = py * 16 + wq * 4 + i;
                const unsigned boff = ((unsigned)(cp << 2)) ^ (((unsigned)p & 7u) << 4);
                *reinterpret_cast<unsigned*>(&xnb[(unsigned)p * 256 + boff]) = pk;
            }
        }
    }
    __syncthreads();
    {
        const int lane   = tid & 63;
        const int wv     = tid >> 6;
        const int lo     = lane & 15;
        const int hi     = lane >> 4;
        const int o_base = wv * 32;
        bf16x8_t afrag[2][4];
        #pragma unroll
        for (int t2 = 0; t2 < 2; ++t2)
            #pragma unroll
            for (int kc = 0; kc < 4; ++kc)
                afrag[t2][kc] = *reinterpret_cast<const bf16x8_t*>(
                    wper + (size_t)(o_base + t2 * 16 + lo) * CC + kc * 32 + hi * 8);
        f32x4_t acc[8][2];
        #pragma unroll
        for (int pt = 0; pt < 8; ++pt) {
            acc[pt][0] = (f32x4_t){0.f, 0.f, 0.f, 0.f};
            acc[pt][1] = (f32x4_t){0.f, 0.f, 0.f, 0.f};
        }
        #pragma unroll
        for (int pt = 0; pt < 8; ++pt) {
            const unsigned rowbase = (unsigned)(pt * 16 + lo) * 256;
            const unsigned sw = (unsigned)((lo & 7) << 4);
            #pragma unroll
            for (int kc = 0; kc < 4; ++kc) {
                bf16x8_t bfrag = *reinterpret_cast<const bf16x8_t*>(
                    &xnb[rowbase + (((unsigned)(kc * 64 + hi * 16)) ^ sw)]);
                acc[pt][0] = __builtin_amdgcn_mfma_f32_16x16x32_bf16(
                    afrag[0][kc], bfrag, acc[pt][0], 0, 0, 0);
                acc[pt][1] = __builtin_amdgcn_mfma_f32_16x16x32_bf16(
                    afrag[1][kc], bfrag, acc[pt][1], 0, 0, 0);
            }
        }
        float iv[2][4], bs[2][4];
        #pragma unroll
        for (int t2 = 0; t2 < 2; ++t2)
            #pragma unroll
            for (int r = 0; r < 4; ++r) {
                const int o = o_base + t2 * 16 + hi * 4 + r;
                iv[t2][r] = invp[o];
                bs[t2][r] = biasp[o];
            }
        #pragma unroll
        for (int pt = 0; pt < 8; ++pt) {
            const int hrow = h0 + pt;
            #pragma unroll
            for (int t2 = 0; t2 < 2; ++t2) {
                #pragma unroll
                for (int r = 0; r < 4; ++r) {
                    const int o = o_base + t2 * 16 + hi * 4 + r;
                    float val = fmaf(acc[pt][t2][r], iv[t2][r], bs[t2][r]);
                    val = fmaxf(val, 0.f);
                    out[((size_t)(bb * CC + o) * HH + hrow) * WW + w0 + lo] = val;
                }
            }
        }
    }
}

extern "C" void kernel_launch(void* const* d_in, const int* in_sizes, int n_in,
                              void* d_out, int out_size, void* d_ws, size_t ws_size,
                              hipStream_t stream) {
    const float* x   = (const float*)d_in[0];
    const float* kk  = (const float*)d_in[1];
    const float* pwt = (const float*)d_in[2];
    const float* g   = (const float*)d_in[3];
    const float* b   = (const float*)d_in[4];
    const float* m   = (const float*)d_in[5];
    const float* v   = (const float*)d_in[6];
    float* out = (float*)d_out;

    unsigned short* wper = (unsigned short*)d_ws;                 // 32 KB
    float* inv  = (float*)((char*)d_ws + 32768);                  // 512 B
    float* bias = (float*)((char*)d_ws + 32768 + 512);            // 512 B
    unsigned short* xn = (unsigned short*)((char*)d_ws + 36864);  // 75.5 MB
    const size_t need = 36864 + (size_t)BB * CC * HH * WW * 2;

    prep_kernel<<<64, 256, 0, stream>>>(pwt, g, b, m, v, wper, inv, bias);
    if (ws_size >= need) {
        dw_kernel<<<dim3(2304), 256, 0, stream>>>(x, kk, xn);
        pw_kernel<<<dim3(2304), 256, 0, stream>>>(xn, wper, inv, bias, out);
    } else {
        fused_main<<<dim3(2304), 256, 0, stream>>>(x, kk, wper, inv, bias, out);
    }
}

// Round 13
// 104.148 us; speedup vs baseline: 1.3101x; 1.2008x over previous
//
#include <hip/hip_runtime.h>
#include <hip/hip_bf16.h>

#define BB 32
#define CC 128
#define HH 96
#define WW 96
#define BN_EPS 1e-5f

typedef __attribute__((ext_vector_type(8))) short bf16x8_t;
typedef __attribute__((ext_vector_type(4))) float f32x4_t;
typedef __attribute__((ext_vector_type(4), aligned(4))) float f32x4u_t;
typedef __attribute__((ext_vector_type(2))) unsigned int u32x2_t;
typedef __attribute__((ext_vector_type(4))) unsigned int u32x4_t;

// ---------------------------------------------------------------------------
// Prep: W fp32 -> bf16, k-permuted (verified). BN folded to inv/bias.
// ---------------------------------------------------------------------------
__global__ __launch_bounds__(256)
void prep_kernel(const float* __restrict__ pw,
                 const float* __restrict__ g, const float* __restrict__ b,
                 const float* __restrict__ m, const float* __restrict__ v,
                 unsigned short* __restrict__ wper,
                 float* __restrict__ inv, float* __restrict__ bias)
{
    int t = blockIdx.x * 256 + threadIdx.x;
    if (t < CC * CC) {
        int o = t >> 7, cidx = t & 127;
        int kc = cidx >> 5, r = cidx & 31, gg = r >> 3, j = r & 7;
        int c = kc * 32 + gg * 4 + (j & 3) + 16 * (j >> 2);
        __hip_bfloat16 h = __float2bfloat16(pw[o * CC + c]);
        wper[o * CC + cidx] = *reinterpret_cast<unsigned short*>(&h);
    }
    if (t < CC) {
        float iv = g[t] * rsqrtf(v[t] + BN_EPS);
        inv[t] = iv;
        bias[t] = b[t] - m[t] * iv;
    }
}

// ---------------------------------------------------------------------------
// Kernel A: depthwise 3x3 (R12 — verified, shuffle halos + wave-edge patch).
// ---------------------------------------------------------------------------
__global__ __launch_bounds__(256, 6)
void dw_kernel(const float* __restrict__ x, const float* __restrict__ kk,
               unsigned short* __restrict__ xn)
{
    const int u = blockIdx.x * 256 + threadIdx.x;
    const int lane = threadIdx.x & 63;
    const int woct = u % 12;
    int t1 = u / 12;
    const int cs = t1 & 127;
    int t2 = t1 >> 7;
    const int th = t2 % 12;
    const int b  = t2 / 12;

    const int kc = cs >> 5, rr = cs & 31, gg = rr >> 3, jj = rr & 7;
    const int c = kc * 32 + gg * 4 + (jj & 3) + 16 * (jj >> 2);

    const int w0 = woct * 8;
    const int h0 = th * 8;
    const bool l_edge = (woct == 0);
    const bool r_edge = (woct == 11);

    const float* plane = x + (size_t)(b * CC + c) * (HH * WW);

    float kw[9];
    {
        const float* kp = kk + (size_t)(b * CC + c) * 9;
        f32x4u_t q0 = *(const f32x4u_t*)(kp);
        f32x4u_t q1 = *(const f32x4u_t*)(kp + 4);
        kw[0]=q0.x; kw[1]=q0.y; kw[2]=q0.z; kw[3]=q0.w;
        kw[4]=q1.x; kw[5]=q1.y; kw[6]=q1.z; kw[7]=q1.w;
        kw[8]=kp[8];
    }

    float rA[10], rB[10], rC[10];
    auto load_row = [&](int row, float* o) {
        const bool valid = (row >= 0) && (row < HH);
        const int rrow = row < 0 ? 0 : (row >= HH ? HH - 1 : row);
        const float* rp = plane + rrow * WW + w0;
        f32x4_t M0 = *(const f32x4_t*)rp;
        f32x4_t M1 = *(const f32x4_t*)(rp + 4);
        float vl = __shfl_up(M1.w, 1);
        float vr = __shfl_down(M0.x, 1);
        if (lane == 0  && !l_edge) vl = rp[-1];
        if (lane == 63 && !r_edge) vr = rp[8];
        o[0] = (valid && !l_edge) ? vl : 0.f;
        o[1] = valid ? M0.x : 0.f;
        o[2] = valid ? M0.y : 0.f;
        o[3] = valid ? M0.z : 0.f;
        o[4] = valid ? M0.w : 0.f;
        o[5] = valid ? M1.x : 0.f;
        o[6] = valid ? M1.y : 0.f;
        o[7] = valid ? M1.z : 0.f;
        o[8] = valid ? M1.w : 0.f;
        o[9] = (valid && !r_edge) ? vr : 0.f;
    };

    load_row(h0 - 1, rA);
    load_row(h0,     rB);

    unsigned short* dst0 = xn + ((size_t)(b * CC + cs) * (HH * WW) + (size_t)h0 * WW + w0);

    #pragma unroll
    for (int py = 0; py < 8; ++py) {
        load_row(h0 + py + 1, rC);

        unsigned pkw[4];
        #pragma unroll
        for (int i = 0; i < 4; ++i) {
            float s0 = 0.f, s1 = 0.f;
            #pragma unroll
            for (int t = 0; t < 3; ++t) {
                s0 = fmaf(rA[2 * i + t],     kw[t],     s0);
                s0 = fmaf(rB[2 * i + t],     kw[3 + t], s0);
                s0 = fmaf(rC[2 * i + t],     kw[6 + t], s0);
                s1 = fmaf(rA[2 * i + 1 + t], kw[t],     s1);
                s1 = fmaf(rB[2 * i + 1 + t], kw[3 + t], s1);
                s1 = fmaf(rC[2 * i + 1 + t], kw[6 + t], s1);
            }
            __hip_bfloat16 h0b = __float2bfloat16(s0);
            __hip_bfloat16 h1b = __float2bfloat16(s1);
            pkw[i] = (unsigned)*reinterpret_cast<unsigned short*>(&h0b)
                   | ((unsigned)*reinterpret_cast<unsigned short*>(&h1b) << 16);
        }
        u32x4_t pk;
        pk.x = pkw[0]; pk.y = pkw[1]; pk.z = pkw[2]; pk.w = pkw[3];
        *reinterpret_cast<u32x4_t*>(dst0 + (size_t)py * WW) = pk;

        #pragma unroll
        for (int t = 0; t < 10; ++t) { rA[t] = rB[t]; rB[t] = rC[t]; }
    }
}

// ---------------------------------------------------------------------------
// Kernel B (R13): pointwise MFMA, 3 h-tiles per block, software-pipelined:
//   stage-loads for tile t+1 issue BEFORE MFMA(t) -> HBM/L2 latency hides
//   under 64 MFMAs + epilogue (T14). wfrag/iv/bs amortized 3x. Single 32KB
//   LDS buffer (write gated by syncs), double REGISTER buffers, fully
//   unrolled (static indexing). Nontemporal out stores (write-once data;
//   keeps xn resident in L2/L3). Grid 768 = 6tw x 4thg x 32b, XCD-swizzled.
// ---------------------------------------------------------------------------
__global__ __launch_bounds__(256, 3)
void pw_kernel(const unsigned short* __restrict__ xn,
               const unsigned short* __restrict__ wper,
               const float* __restrict__ invp, const float* __restrict__ biasp,
               float* __restrict__ out)
{
    __shared__ __align__(16) unsigned char xnb[128 * 256];
    const int tid = threadIdx.x;

    // chunked XCD swizzle (768 = 8 x 96)
    const unsigned wg  = blockIdx.x;
    const unsigned nid = (wg & 7u) * 96u + (wg >> 3);
    const int tw  = nid % 6u;
    const int thg = (nid / 6u) % 4u;
    const int b   = nid / 24u;
    const int w0  = tw * 16;

    const int lane   = tid & 63;
    const int wv     = tid >> 6;
    const int lo     = lane & 15;
    const int hi     = lane >> 4;
    const int o_base = wv * 32;

    // fixed per block: W fragments + BN consts (amortized over 3 tiles)
    bf16x8_t wfrag[2][4];
    #pragma unroll
    for (int t2 = 0; t2 < 2; ++t2)
        #pragma unroll
        for (int kc = 0; kc < 4; ++kc)
            wfrag[t2][kc] = *reinterpret_cast<const bf16x8_t*>(
                wper + (size_t)(o_base + t2 * 16 + lo) * CC + kc * 32 + hi * 8);

    float iv2[2], bs2[2];
    #pragma unroll
    for (int t2 = 0; t2 < 2; ++t2) {
        iv2[t2] = invp[o_base + t2 * 16 + lo];
        bs2[t2] = biasp[o_base + t2 * 16 + lo];
    }

    const int cs4 = tid >> 3;
    const int py  = tid & 7;
    const unsigned short* src_base =
        xn + (size_t)(b * CC + cs4 * 4) * (HH * WW) + (size_t)py * WW + w0;

    unsigned dLA[4][4], dRA[4][4], dLB[4][4], dRB[4][4];

    auto LOADREGS = [&](int t, unsigned (*dL)[4], unsigned (*dR)[4]) {
        const unsigned short* s0 = src_base + (size_t)((thg * 3 + t) * 8) * WW;
        #pragma unroll
        for (int q = 0; q < 4; ++q) {
            const unsigned short* src = s0 + (size_t)q * (HH * WW);
            u32x4_t L = *(const u32x4_t*)src;
            u32x4_t R = *(const u32x4_t*)(src + 8);
            dL[q][0]=L.x; dL[q][1]=L.y; dL[q][2]=L.z; dL[q][3]=L.w;
            dR[q][0]=R.x; dR[q][1]=R.y; dR[q][2]=R.z; dR[q][3]=R.w;
        }
    };

    auto WRITE_LDS = [&](unsigned (*dL)[4], unsigned (*dR)[4]) {
        #pragma unroll
        for (int o8 = 0; o8 < 2; ++o8) {
            #pragma unroll
            for (int j = 0; j < 4; ++j) {
                const unsigned d0 = o8 ? dR[0][j] : dL[0][j];
                const unsigned d1 = o8 ? dR[1][j] : dL[1][j];
                const unsigned d2 = o8 ? dR[2][j] : dL[2][j];
                const unsigned d3 = o8 ? dR[3][j] : dL[3][j];
                u32x2_t we, wo;
                we.x = __builtin_amdgcn_perm(d1, d0, 0x05040100u);
                we.y = __builtin_amdgcn_perm(d3, d2, 0x05040100u);
                wo.x = __builtin_amdgcn_perm(d1, d0, 0x07060302u);
                wo.y = __builtin_amdgcn_perm(d3, d2, 0x07060302u);
                const int pe = py * 16 + o8 * 8 + 2 * j;
                const int po = pe + 1;
                *reinterpret_cast<u32x2_t*>(&xnb[(unsigned)pe * 256 +
                    (((unsigned)cs4 * 8) ^ (((unsigned)pe & 7u) << 4))]) = we;
                *reinterpret_cast<u32x2_t*>(&xnb[(unsigned)po * 256 +
                    (((unsigned)cs4 * 8) ^ (((unsigned)po & 7u) << 4))]) = wo;
            }
        }
    };

    auto COMPUTE = [&](int t) {
        const int h0 = (thg * 3 + t) * 8;
        f32x4_t acc[8][2];
        #pragma unroll
        for (int pt = 0; pt < 8; ++pt) {
            acc[pt][0] = (f32x4_t){0.f, 0.f, 0.f, 0.f};
            acc[pt][1] = (f32x4_t){0.f, 0.f, 0.f, 0.f};
        }
        #pragma unroll
        for (int pt = 0; pt < 8; ++pt) {
            const unsigned rowbase = (unsigned)(pt * 16 + lo) * 256;
            const unsigned sw = (unsigned)((lo & 7) << 4);
            #pragma unroll
            for (int kc = 0; kc < 4; ++kc) {
                bf16x8_t xfrag = *reinterpret_cast<const bf16x8_t*>(
                    &xnb[rowbase + (((unsigned)(kc * 64 + hi * 16)) ^ sw)]);
                acc[pt][0] = __builtin_amdgcn_mfma_f32_16x16x32_bf16(
                    xfrag, wfrag[0][kc], acc[pt][0], 0, 0, 0);
                acc[pt][1] = __builtin_amdgcn_mfma_f32_16x16x32_bf16(
                    xfrag, wfrag[1][kc], acc[pt][1], 0, 0, 0);
            }
        }
        #pragma unroll
        for (int pt = 0; pt < 8; ++pt) {
            const int hrow = h0 + pt;
            #pragma unroll
            for (int t2 = 0; t2 < 2; ++t2) {
                const int o = o_base + t2 * 16 + lo;
                f32x4_t vv;
                #pragma unroll
                for (int r = 0; r < 4; ++r)
                    vv[r] = fmaxf(fmaf(acc[pt][t2][r], iv2[t2], bs2[t2]), 0.f);
                __builtin_nontemporal_store(vv, reinterpret_cast<f32x4_t*>(
                    out + ((size_t)(b * CC + o) * HH + hrow) * WW + w0 + hi * 4));
            }
        }
    };

    // ---- pipelined schedule: stage(t+1) issues before MFMA(t) ----
    LOADREGS(0, dLA, dRA);
    WRITE_LDS(dLA, dRA);          // no sync needed before first write
    LOADREGS(1, dLB, dRB);        // in flight during COMPUTE(0)
    __syncthreads();
    COMPUTE(0);
    __syncthreads();
    WRITE_LDS(dLB, dRB);
    LOADREGS(2, dLA, dRA);        // in flight during COMPUTE(1)
    __syncthreads();
    COMPUTE(1);
    __syncthreads();
    WRITE_LDS(dLA, dRA);
    __syncthreads();
    COMPUTE(2);
}

// ---------------------------------------------------------------------------
// Fallback (ws too small): R5 fused kernel.
// ---------------------------------------------------------------------------
__global__ __launch_bounds__(256, 3)
void fused_main(const float* __restrict__ x, const float* __restrict__ kk,
                const unsigned short* __restrict__ wper,
                const float* __restrict__ invp, const float* __restrict__ biasp,
                float* __restrict__ out)
{
    __shared__ __align__(16) unsigned char xnb[128 * 256];
    const int tid = threadIdx.x;
    const unsigned wg  = blockIdx.x;
    const unsigned nid = (wg & 7u) * 288u + (wg >> 3);
    const int bx = nid % 6u;
    const int by = (nid / 6u) % 12u;
    const int bb = nid / 72u;
    const int w0 = bx * 16;
    const int h0 = by * 8;
    {
        const int wq = tid & 3;
        const int cp = tid >> 2;
        const int s  = cp << 1;
        const int kc = s >> 5, rr = s & 31, gg = rr >> 3, jj = rr & 7;
        const int cA = kc * 32 + gg * 4 + (jj & 3) + 16 * (jj >> 2);
        const int gw = w0 + wq * 4;
        const bool l_edge = (gw == 0);
        const bool r_edge = (gw + 4 >= WW);
        const float* planeA = x + (size_t)(bb * CC + cA) * (HH * WW);
        float kwA[9], kwB[9];
        {
            const float* kp = kk + (size_t)(bb * CC + cA) * 9;
            f32x4u_t q0 = *(const f32x4u_t*)(kp + 0);
            f32x4u_t q1 = *(const f32x4u_t*)(kp + 4);
            f32x4u_t q2 = *(const f32x4u_t*)(kp + 8);
            f32x4u_t q3 = *(const f32x4u_t*)(kp + 12);
            float     e16 = kp[16], e17 = kp[17];
            kwA[0]=q0.x; kwA[1]=q0.y; kwA[2]=q0.z; kwA[3]=q0.w;
            kwA[4]=q1.x; kwA[5]=q1.y; kwA[6]=q1.z; kwA[7]=q1.w;
            kwA[8]=q2.x;
            kwB[0]=q2.y; kwB[1]=q2.z; kwB[2]=q2.w;
            kwB[3]=q3.x; kwB[4]=q3.y; kwB[5]=q3.z; kwB[6]=q3.w;
            kwB[7]=e16;  kwB[8]=e17;
        }
        float xd[2][10][6];
        #pragma unroll
        for (int q = 0; q < 2; ++q) {
            const float* plane = planeA + q * (HH * WW);
            #pragma unroll
            for (int r = 0; r < 10; ++r) {
                const int row = h0 - 1 + r;
                const bool valid = (row >= 0) && (row < HH);
                const int rrow = row < 0 ? 0 : (row >= HH ? HH - 1 : row);
                const float* rp = plane + rrow * WW + gw;
                f32x4_t M = *(const f32x4_t*)rp;
                float vl = rp[l_edge ? 0 : -1];
                float vr = rp[r_edge ? 3 : 4];
                xd[q][r][0] = (valid && !l_edge) ? vl : 0.f;
                xd[q][r][1] = valid ? M.x : 0.f;
                xd[q][r][2] = valid ? M.y : 0.f;
                xd[q][r][3] = valid ? M.z : 0.f;
                xd[q][r][4] = valid ? M.w : 0.f;
                xd[q][r][5] = (valid && !r_edge) ? vr : 0.f;
            }
        }
        #pragma unroll
        for (int py = 0; py < 8; ++py) {
            #pragma unroll
            for (int i = 0; i < 4; ++i) {
                float sA = 0.f, sB = 0.f;
                #pragma unroll
                for (int t = 0; t < 3; ++t) {
                    sA = fmaf(xd[0][py + 0][i + t], kwA[t],     sA);
                    sA = fmaf(xd[0][py + 1][i + t], kwA[3 + t], sA);
                    sA = fmaf(xd[0][py + 2][i + t], kwA[6 + t], sA);
                    sB = fmaf(xd[1][py + 0][i + t], kwB[t],     sB);
                    sB = fmaf(xd[1][py + 1][i + t], kwB[3 + t], sB);
                    sB = fmaf(xd[1][py + 2][i + t], kwB[6 + t], sB);
                }
                __hip_bfloat16 hA = __float2bfloat16(sA);
                __hip_bfloat16 hB = __float2bfloat16(sB);
                unsigned pk = (unsigned)*reinterpret_cast<unsigned short*>(&hA)
                            | ((unsigned)*reinterpret_cast<unsigned short*>(&hB) << 16);
                const int p = py * 16 + wq * 4 + i;
                const unsigned boff = ((unsigned)(cp << 2)) ^ (((unsigned)p & 7u) << 4);
                *reinterpret_cast<unsigned*>(&xnb[(unsigned)p * 256 + boff]) = pk;
            }
        }
    }
    __syncthreads();
    {
        const int lane   = tid & 63;
        const int wv     = tid >> 6;
        const int lo     = lane & 15;
        const int hi     = lane >> 4;
        const int o_base = wv * 32;
        bf16x8_t afrag[2][4];
        #pragma unroll
        for (int t2 = 0; t2 < 2; ++t2)
            #pragma unroll
            for (int kc = 0; kc < 4; ++kc)
                afrag[t2][kc] = *reinterpret_cast<const bf16x8_t*>(
                    wper + (size_t)(o_base + t2 * 16 + lo) * CC + kc * 32 + hi * 8);
        f32x4_t acc[8][2];
        #pragma unroll
        for (int pt = 0; pt < 8; ++pt) {
            acc[pt][0] = (f32x4_t){0.f, 0.f, 0.f, 0.f};
            acc[pt][1] = (f32x4_t){0.f, 0.f, 0.f, 0.f};
        }
        #pragma unroll
        for (int pt = 0; pt < 8; ++pt) {
            const unsigned rowbase = (unsigned)(pt * 16 + lo) * 256;
            const unsigned sw = (unsigned)((lo & 7) << 4);
            #pragma unroll
            for (int kc = 0; kc < 4; ++kc) {
                bf16x8_t bfrag = *reinterpret_cast<const bf16x8_t*>(
                    &xnb[rowbase + (((unsigned)(kc * 64 + hi * 16)) ^ sw)]);
                acc[pt][0] = __builtin_amdgcn_mfma_f32_16x16x32_bf16(
                    afrag[0][kc], bfrag, acc[pt][0], 0, 0, 0);
                acc[pt][1] = __builtin_amdgcn_mfma_f32_16x16x32_bf16(
                    afrag[1][kc], bfrag, acc[pt][1], 0, 0, 0);
            }
        }
        float iv[2][4], bs[2][4];
        #pragma unroll
        for (int t2 = 0; t2 < 2; ++t2)
            #pragma unroll
            for (int r = 0; r < 4; ++r) {
                const int o = o_base + t2 * 16 + hi * 4 + r;
                iv[t2][r] = invp[o];
                bs[t2][r] = biasp[o];
            }
        #pragma unroll
        for (int pt = 0; pt < 8; ++pt) {
            const int hrow = h0 + pt;
            #pragma unroll
            for (int t2 = 0; t2 < 2; ++t2) {
                #pragma unroll
                for (int r = 0; r < 4; ++r) {
                    const int o = o_base + t2 * 16 + hi * 4 + r;
                    float val = fmaf(acc[pt][t2][r], iv[t2][r], bs[t2][r]);
                    val = fmaxf(val, 0.f);
                    out[((size_t)(bb * CC + o) * HH + hrow) * WW + w0 + lo] = val;
                }
            }
        }
    }
}

extern "C" void kernel_launch(void* const* d_in, const int* in_sizes, int n_in,
                              void* d_out, int out_size, void* d_ws, size_t ws_size,
                              hipStream_t stream) {
    const float* x   = (const float*)d_in[0];
    const float* kk  = (const float*)d_in[1];
    const float* pwt = (const float*)d_in[2];
    const float* g   = (const float*)d_in[3];
    const float* b   = (const float*)d_in[4];
    const float* m   = (const float*)d_in[5];
    const float* v   = (const float*)d_in[6];
    float* out = (float*)d_out;

    unsigned short* wper = (unsigned short*)d_ws;                 // 32 KB
    float* inv  = (float*)((char*)d_ws + 32768);                  // 512 B
    float* bias = (float*)((char*)d_ws + 32768 + 512);            // 512 B
    unsigned short* xn = (unsigned short*)((char*)d_ws + 36864);  // 75.5 MB
    const size_t need = 36864 + (size_t)BB * CC * HH * WW * 2;

    prep_kernel<<<64, 256, 0, stream>>>(pwt, g, b, m, v, wper, inv, bias);
    if (ws_size >= need) {
        dw_kernel<<<dim3(2304), 256, 0, stream>>>(x, kk, xn);
        pw_kernel<<<dim3(768), 256, 0, stream>>>(xn, wper, inv, bias, out);
    } else {
        fused_main<<<dim3(2304), 256, 0, stream>>>(x, kk, wper, inv, bias, out);
    }
}

// Round 14
// 98.844 us; speedup vs baseline: 1.3804x; 1.0537x over previous
//
#include <hip/hip_runtime.h>
#include <hip/hip_bf16.h>

#define BB 32
#define CC 128
#define HH 96
#define WW 96
#define BN_EPS 1e-5f

typedef __attribute__((ext_vector_type(8))) short bf16x8_t;
typedef __attribute__((ext_vector_type(4))) float f32x4_t;
typedef __attribute__((ext_vector_type(4), aligned(4))) float f32x4u_t;
typedef __attribute__((ext_vector_type(2))) unsigned int u32x2_t;
typedef __attribute__((ext_vector_type(4))) unsigned int u32x4_t;

// ---------------------------------------------------------------------------
// Prep: W fp32 -> bf16, k-permuted (verified). BN folded to inv/bias.
// ---------------------------------------------------------------------------
__global__ __launch_bounds__(256)
void prep_kernel(const float* __restrict__ pw,
                 const float* __restrict__ g, const float* __restrict__ b,
                 const float* __restrict__ m, const float* __restrict__ v,
                 unsigned short* __restrict__ wper,
                 float* __restrict__ inv, float* __restrict__ bias)
{
    int t = blockIdx.x * 256 + threadIdx.x;
    if (t < CC * CC) {
        int o = t >> 7, cidx = t & 127;
        int kc = cidx >> 5, r = cidx & 31, gg = r >> 3, j = r & 7;
        int c = kc * 32 + gg * 4 + (j & 3) + 16 * (j >> 2);
        __hip_bfloat16 h = __float2bfloat16(pw[o * CC + c]);
        wper[o * CC + cidx] = *reinterpret_cast<unsigned short*>(&h);
    }
    if (t < CC) {
        float iv = g[t] * rsqrtf(v[t] + BN_EPS);
        inv[t] = iv;
        bias[t] = b[t] - m[t] * iv;
    }
}

// ---------------------------------------------------------------------------
// Kernel A (R14): depthwise 3x3, ONE output row per thread — the 3 row-loads
// are fully INDEPENDENT (no sliding window, nothing for the compiler to
// chain; R13 counters showed VGPR=32 with ~2 loads in flight = 85us).
// Halos via shuffle + wave-edge patch (R12-verified). 18432 blocks, chunked
// XCD swizzle (18432 % 8 == 0): blocks of one (b,cs)-plane stay XCD-local
// so the h-halo is an L2 hit, HBM read amp ~1.08x.
// ---------------------------------------------------------------------------
__global__ __launch_bounds__(256, 6)
void dw_kernel(const float* __restrict__ x, const float* __restrict__ kk,
               unsigned short* __restrict__ xn)
{
    const unsigned wg  = blockIdx.x;
    const unsigned bid = (wg & 7u) * 2304u + (wg >> 3);   // bijective on [0,18432)
    const int u = (int)bid * 256 + threadIdx.x;           // (((b*128+cs)*96)+h)*12+woct
    const int lane = threadIdx.x & 63;
    const int woct = u % 12;
    int t1 = u / 12;
    const int h = t1 % HH;
    int t2 = t1 / HH;
    const int cs = t2 & 127;
    const int b  = t2 >> 7;

    // storage -> actual channel permutation
    const int kc = cs >> 5, rr = cs & 31, gg = rr >> 3, jj = rr & 7;
    const int c = kc * 32 + gg * 4 + (jj & 3) + 16 * (jj >> 2);

    const int w0 = woct * 8;
    const bool l_edge = (woct == 0);
    const bool r_edge = (woct == 11);

    const float* plane = x + (size_t)(b * CC + c) * (HH * WW);

    float kw[9];
    {
        const float* kp = kk + (size_t)(b * CC + c) * 9;
        f32x4u_t q0 = *(const f32x4u_t*)(kp);
        f32x4u_t q1 = *(const f32x4u_t*)(kp + 4);
        kw[0]=q0.x; kw[1]=q0.y; kw[2]=q0.z; kw[3]=q0.w;
        kw[4]=q1.x; kw[5]=q1.y; kw[6]=q1.z; kw[7]=q1.w;
        kw[8]=kp[8];
    }

    float r0[10], r1[10], r2[10];
    auto load_row = [&](int row, float* o) {
        const bool valid = (row >= 0) && (row < HH);
        const int rrow = row < 0 ? 0 : (row >= HH ? HH - 1 : row);
        const float* rp = plane + rrow * WW + w0;   // 32B aligned
        f32x4_t M0 = *(const f32x4_t*)rp;
        f32x4_t M1 = *(const f32x4_t*)(rp + 4);
        float vl = __shfl_up(M1.w, 1);              // lane-1's px7 = x[w0-1]
        float vr = __shfl_down(M0.x, 1);            // lane+1's px0 = x[w0+8]
        if (lane == 0  && !l_edge) vl = rp[-1];     // wave-edge patch (R12)
        if (lane == 63 && !r_edge) vr = rp[8];
        o[0] = (valid && !l_edge) ? vl : 0.f;
        o[1] = valid ? M0.x : 0.f;
        o[2] = valid ? M0.y : 0.f;
        o[3] = valid ? M0.z : 0.f;
        o[4] = valid ? M0.w : 0.f;
        o[5] = valid ? M1.x : 0.f;
        o[6] = valid ? M1.y : 0.f;
        o[7] = valid ? M1.z : 0.f;
        o[8] = valid ? M1.w : 0.f;
        o[9] = (valid && !r_edge) ? vr : 0.f;
    };

    // three INDEPENDENT row loads — issue together, wait once
    load_row(h - 1, r0);
    load_row(h,     r1);
    load_row(h + 1, r2);

    unsigned pkw[4];
    #pragma unroll
    for (int i = 0; i < 4; ++i) {
        float s0 = 0.f, s1 = 0.f;
        #pragma unroll
        for (int t = 0; t < 3; ++t) {
            s0 = fmaf(r0[2 * i + t],     kw[t],     s0);
            s0 = fmaf(r1[2 * i + t],     kw[3 + t], s0);
            s0 = fmaf(r2[2 * i + t],     kw[6 + t], s0);
            s1 = fmaf(r0[2 * i + 1 + t], kw[t],     s1);
            s1 = fmaf(r1[2 * i + 1 + t], kw[3 + t], s1);
            s1 = fmaf(r2[2 * i + 1 + t], kw[6 + t], s1);
        }
        __hip_bfloat16 h0b = __float2bfloat16(s0);
        __hip_bfloat16 h1b = __float2bfloat16(s1);
        pkw[i] = (unsigned)*reinterpret_cast<unsigned short*>(&h0b)
               | ((unsigned)*reinterpret_cast<unsigned short*>(&h1b) << 16);
    }
    u32x4_t pk;
    pk.x = pkw[0]; pk.y = pkw[1]; pk.z = pkw[2]; pk.w = pkw[3];
    unsigned short* dst = xn + ((size_t)(b * CC + cs) * (HH * WW) + (size_t)h * WW + w0);
    *reinterpret_cast<u32x4_t*>(dst) = pk;    // 16B aligned, coalesced
}

// ---------------------------------------------------------------------------
// Kernel B (R13 — verified): pointwise MFMA, 3 h-tiles/block, software-
// pipelined staging, nontemporal stores. Grid 768, XCD-swizzled.
// ---------------------------------------------------------------------------
__global__ __launch_bounds__(256, 3)
void pw_kernel(const unsigned short* __restrict__ xn,
               const unsigned short* __restrict__ wper,
               const float* __restrict__ invp, const float* __restrict__ biasp,
               float* __restrict__ out)
{
    __shared__ __align__(16) unsigned char xnb[128 * 256];
    const int tid = threadIdx.x;

    const unsigned wg  = blockIdx.x;
    const unsigned nid = (wg & 7u) * 96u + (wg >> 3);
    const int tw  = nid % 6u;
    const int thg = (nid / 6u) % 4u;
    const int b   = nid / 24u;
    const int w0  = tw * 16;

    const int lane   = tid & 63;
    const int wv     = tid >> 6;
    const int lo     = lane & 15;
    const int hi     = lane >> 4;
    const int o_base = wv * 32;

    bf16x8_t wfrag[2][4];
    #pragma unroll
    for (int t2 = 0; t2 < 2; ++t2)
        #pragma unroll
        for (int kc = 0; kc < 4; ++kc)
            wfrag[t2][kc] = *reinterpret_cast<const bf16x8_t*>(
                wper + (size_t)(o_base + t2 * 16 + lo) * CC + kc * 32 + hi * 8);

    float iv2[2], bs2[2];
    #pragma unroll
    for (int t2 = 0; t2 < 2; ++t2) {
        iv2[t2] = invp[o_base + t2 * 16 + lo];
        bs2[t2] = biasp[o_base + t2 * 16 + lo];
    }

    const int cs4 = tid >> 3;
    const int py  = tid & 7;
    const unsigned short* src_base =
        xn + (size_t)(b * CC + cs4 * 4) * (HH * WW) + (size_t)py * WW + w0;

    unsigned dLA[4][4], dRA[4][4], dLB[4][4], dRB[4][4];

    auto LOADREGS = [&](int t, unsigned (*dL)[4], unsigned (*dR)[4]) {
        const unsigned short* s0 = src_base + (size_t)((thg * 3 + t) * 8) * WW;
        #pragma unroll
        for (int q = 0; q < 4; ++q) {
            const unsigned short* src = s0 + (size_t)q * (HH * WW);
            u32x4_t L = *(const u32x4_t*)src;
            u32x4_t R = *(const u32x4_t*)(src + 8);
            dL[q][0]=L.x; dL[q][1]=L.y; dL[q][2]=L.z; dL[q][3]=L.w;
            dR[q][0]=R.x; dR[q][1]=R.y; dR[q][2]=R.z; dR[q][3]=R.w;
        }
    };

    auto WRITE_LDS = [&](unsigned (*dL)[4], unsigned (*dR)[4]) {
        #pragma unroll
        for (int o8 = 0; o8 < 2; ++o8) {
            #pragma unroll
            for (int j = 0; j < 4; ++j) {
                const unsigned d0 = o8 ? dR[0][j] : dL[0][j];
                const unsigned d1 = o8 ? dR[1][j] : dL[1][j];
                const unsigned d2 = o8 ? dR[2][j] : dL[2][j];
                const unsigned d3 = o8 ? dR[3][j] : dL[3][j];
                u32x2_t we, wo;
                we.x = __builtin_amdgcn_perm(d1, d0, 0x05040100u);
                we.y = __builtin_amdgcn_perm(d3, d2, 0x05040100u);
                wo.x = __builtin_amdgcn_perm(d1, d0, 0x07060302u);
                wo.y = __builtin_amdgcn_perm(d3, d2, 0x07060302u);
                const int pe = py * 16 + o8 * 8 + 2 * j;
                const int po = pe + 1;
                *reinterpret_cast<u32x2_t*>(&xnb[(unsigned)pe * 256 +
                    (((unsigned)cs4 * 8) ^ (((unsigned)pe & 7u) << 4))]) = we;
                *reinterpret_cast<u32x2_t*>(&xnb[(unsigned)po * 256 +
                    (((unsigned)cs4 * 8) ^ (((unsigned)po & 7u) << 4))]) = wo;
            }
        }
    };

    auto COMPUTE = [&](int t) {
        const int h0 = (thg * 3 + t) * 8;
        f32x4_t acc[8][2];
        #pragma unroll
        for (int pt = 0; pt < 8; ++pt) {
            acc[pt][0] = (f32x4_t){0.f, 0.f, 0.f, 0.f};
            acc[pt][1] = (f32x4_t){0.f, 0.f, 0.f, 0.f};
        }
        #pragma unroll
        for (int pt = 0; pt < 8; ++pt) {
            const unsigned rowbase = (unsigned)(pt * 16 + lo) * 256;
            const unsigned sw = (unsigned)((lo & 7) << 4);
            #pragma unroll
            for (int kc = 0; kc < 4; ++kc) {
                bf16x8_t xfrag = *reinterpret_cast<const bf16x8_t*>(
                    &xnb[rowbase + (((unsigned)(kc * 64 + hi * 16)) ^ sw)]);
                acc[pt][0] = __builtin_amdgcn_mfma_f32_16x16x32_bf16(
                    xfrag, wfrag[0][kc], acc[pt][0], 0, 0, 0);
                acc[pt][1] = __builtin_amdgcn_mfma_f32_16x16x32_bf16(
                    xfrag, wfrag[1][kc], acc[pt][1], 0, 0, 0);
            }
        }
        #pragma unroll
        for (int pt = 0; pt < 8; ++pt) {
            const int hrow = h0 + pt;
            #pragma unroll
            for (int t2 = 0; t2 < 2; ++t2) {
                const int o = o_base + t2 * 16 + lo;
                f32x4_t vv;
                #pragma unroll
                for (int r = 0; r < 4; ++r)
                    vv[r] = fmaxf(fmaf(acc[pt][t2][r], iv2[t2], bs2[t2]), 0.f);
                __builtin_nontemporal_store(vv, reinterpret_cast<f32x4_t*>(
                    out + ((size_t)(b * CC + o) * HH + hrow) * WW + w0 + hi * 4));
            }
        }
    };

    LOADREGS(0, dLA, dRA);
    WRITE_LDS(dLA, dRA);
    LOADREGS(1, dLB, dRB);
    __syncthreads();
    COMPUTE(0);
    __syncthreads();
    WRITE_LDS(dLB, dRB);
    LOADREGS(2, dLA, dRA);
    __syncthreads();
    COMPUTE(1);
    __syncthreads();
    WRITE_LDS(dLA, dRA);
    __syncthreads();
    COMPUTE(2);
}

// ---------------------------------------------------------------------------
// Fallback (ws too small): R5 fused kernel.
// ---------------------------------------------------------------------------
__global__ __launch_bounds__(256, 3)
void fused_main(const float* __restrict__ x, const float* __restrict__ kk,
                const unsigned short* __restrict__ wper,
                const float* __restrict__ invp, const float* __restrict__ biasp,
                float* __restrict__ out)
{
    __shared__ __align__(16) unsigned char xnb[128 * 256];
    const int tid = threadIdx.x;
    const unsigned wg  = blockIdx.x;
    const unsigned nid = (wg & 7u) * 288u + (wg >> 3);
    const int bx = nid % 6u;
    const int by = (nid / 6u) % 12u;
    const int bb = nid / 72u;
    const int w0 = bx * 16;
    const int h0 = by * 8;
    {
        const int wq = tid & 3;
        const int cp = tid >> 2;
        const int s  = cp << 1;
        const int kc = s >> 5, rr = s & 31, gg = rr >> 3, jj = rr & 7;
        const int cA = kc * 32 + gg * 4 + (jj & 3) + 16 * (jj >> 2);
        const int gw = w0 + wq * 4;
        const bool l_edge = (gw == 0);
        const bool r_edge = (gw + 4 >= WW);
        const float* planeA = x + (size_t)(bb * CC + cA) * (HH * WW);
        float kwA[9], kwB[9];
        {
            const float* kp = kk + (size_t)(bb * CC + cA) * 9;
            f32x4u_t q0 = *(const f32x4u_t*)(kp + 0);
            f32x4u_t q1 = *(const f32x4u_t*)(kp + 4);
            f32x4u_t q2 = *(const f32x4u_t*)(kp + 8);
            f32x4u_t q3 = *(const f32x4u_t*)(kp + 12);
            float     e16 = kp[16], e17 = kp[17];
            kwA[0]=q0.x; kwA[1]=q0.y; kwA[2]=q0.z; kwA[3]=q0.w;
            kwA[4]=q1.x; kwA[5]=q1.y; kwA[6]=q1.z; kwA[7]=q1.w;
            kwA[8]=q2.x;
            kwB[0]=q2.y; kwB[1]=q2.z; kwB[2]=q2.w;
            kwB[3]=q3.x; kwB[4]=q3.y; kwB[5]=q3.z; kwB[6]=q3.w;
            kwB[7]=e16;  kwB[8]=e17;
        }
        float xd[2][10][6];
        #pragma unroll
        for (int q = 0; q < 2; ++q) {
            const float* plane = planeA + q * (HH * WW);
            #pragma unroll
            for (int r = 0; r < 10; ++r) {
                const int row = h0 - 1 + r;
                const bool valid = (row >= 0) && (row < HH);
                const int rrow = row < 0 ? 0 : (row >= HH ? HH - 1 : row);
                const float* rp = plane + rrow * WW + gw;
                f32x4_t M = *(const f32x4_t*)rp;
                float vl = rp[l_edge ? 0 : -1];
                float vr = rp[r_edge ? 3 : 4];
                xd[q][r][0] = (valid && !l_edge) ? vl : 0.f;
                xd[q][r][1] = valid ? M.x : 0.f;
                xd[q][r][2] = valid ? M.y : 0.f;
                xd[q][r][3] = valid ? M.z : 0.f;
                xd[q][r][4] = valid ? M.w : 0.f;
                xd[q][r][5] = (valid && !r_edge) ? vr : 0.f;
            }
        }
        #pragma unroll
        for (int py = 0; py < 8; ++py) {
            #pragma unroll
            for (int i = 0; i < 4; ++i) {
                float sA = 0.f, sB = 0.f;
                #pragma unroll
                for (int t = 0; t < 3; ++t) {
                    sA = fmaf(xd[0][py + 0][i + t], kwA[t],     sA);
                    sA = fmaf(xd[0][py + 1][i + t], kwA[3 + t], sA);
                    sA = fmaf(xd[0][py + 2][i + t], kwA[6 + t], sA);
                    sB = fmaf(xd[1][py + 0][i + t], kwB[t],     sB);
                    sB = fmaf(xd[1][py + 1][i + t], kwB[3 + t], sB);
                    sB = fmaf(xd[1][py + 2][i + t], kwB[6 + t], sB);
                }
                __hip_bfloat16 hA = __float2bfloat16(sA);
                __hip_bfloat16 hB = __float2bfloat16(sB);
                unsigned pk = (unsigned)*reinterpret_cast<unsigned short*>(&hA)
                            | ((unsigned)*reinterpret_cast<unsigned short*>(&hB) << 16);
                const int p = py * 16 + wq * 4 + i;
                const unsigned boff = ((unsigned)(cp << 2)) ^ (((unsigned)p & 7u) << 4);
                *reinterpret_cast<unsigned*>(&xnb[(unsigned)p * 256 + boff]) = pk;
            }
        }
    }
    __syncthreads();
    {
        const int lane   = tid & 63;
        const int wv     = tid >> 6;
        const int lo     = lane & 15;
        const int hi     = lane >> 4;
        const int o_base = wv * 32;
        bf16x8_t afrag[2][4];
        #pragma unroll
        for (int t2 = 0; t2 < 2; ++t2)
            #pragma unroll
            for (int kc = 0; kc < 4; ++kc)
                afrag[t2][kc] = *reinterpret_cast<const bf16x8_t*>(
                    wper + (size_t)(o_base + t2 * 16 + lo) * CC + kc * 32 + hi * 8);
        f32x4_t acc[8][2];
        #pragma unroll
        for (int pt = 0; pt < 8; ++pt) {
            acc[pt][0] = (f32x4_t){0.f, 0.f, 0.f, 0.f};
            acc[pt][1] = (f32x4_t){0.f, 0.f, 0.f, 0.f};
        }
        #pragma unroll
        for (int pt = 0; pt < 8; ++pt) {
            const unsigned rowbase = (unsigned)(pt * 16 + lo) * 256;
            const unsigned sw = (unsigned)((lo & 7) << 4);
            #pragma unroll
            for (int kc = 0; kc < 4; ++kc) {
                bf16x8_t bfrag = *reinterpret_cast<const bf16x8_t*>(
                    &xnb[rowbase + (((unsigned)(kc * 64 + hi * 16)) ^ sw)]);
                acc[pt][0] = __builtin_amdgcn_mfma_f32_16x16x32_bf16(
                    afrag[0][kc], bfrag, acc[pt][0], 0, 0, 0);
                acc[pt][1] = __builtin_amdgcn_mfma_f32_16x16x32_bf16(
                    afrag[1][kc], bfrag, acc[pt][1], 0, 0, 0);
            }
        }
        float iv[2][4], bs[2][4];
        #pragma unroll
        for (int t2 = 0; t2 < 2; ++t2)
            #pragma unroll
            for (int r = 0; r < 4; ++r) {
                const int o = o_base + t2 * 16 + hi * 4 + r;
                iv[t2][r] = invp[o];
                bs[t2][r] = biasp[o];
            }
        #pragma unroll
        for (int pt = 0; pt < 8; ++pt) {
            const int hrow = h0 + pt;
            #pragma unroll
            for (int t2 = 0; t2 < 2; ++t2) {
                #pragma unroll
                for (int r = 0; r < 4; ++r) {
                    const int o = o_base + t2 * 16 + hi * 4 + r;
                    float val = fmaf(acc[pt][t2][r], iv[t2][r], bs[t2][r]);
                    val = fmaxf(val, 0.f);
                    out[((size_t)(bb * CC + o) * HH + hrow) * WW + w0 + lo] = val;
                }
            }
        }
    }
}

extern "C" void kernel_launch(void* const* d_in, const int* in_sizes, int n_in,
                              void* d_out, int out_size, void* d_ws, size_t ws_size,
                              hipStream_t stream) {
    const float* x   = (const float*)d_in[0];
    const float* kk  = (const float*)d_in[1];
    const float* pwt = (const float*)d_in[2];
    const float* g   = (const float*)d_in[3];
    const float* b   = (const float*)d_in[4];
    const float* m   = (const float*)d_in[5];
    const float* v   = (const float*)d_in[6];
    float* out = (float*)d_out;

    unsigned short* wper = (unsigned short*)d_ws;                 // 32 KB
    float* inv  = (float*)((char*)d_ws + 32768);                  // 512 B
    float* bias = (float*)((char*)d_ws + 32768 + 512);            // 512 B
    unsigned short* xn = (unsigned short*)((char*)d_ws + 36864);  // 75.5 MB
    const size_t need = 36864 + (size_t)BB * CC * HH * WW * 2;

    prep_kernel<<<64, 256, 0, stream>>>(pwt, g, b, m, v, wper, inv, bias);
    if (ws_size >= need) {
        dw_kernel<<<dim3(18432), 256, 0, stream>>>(x, kk, xn);
        pw_kernel<<<dim3(768), 256, 0, stream>>>(xn, wper, inv, bias, out);
    } else {
        fused_main<<<dim3(2304), 256, 0, stream>>>(x, kk, wper, inv, bias, out);
    }
}

// Round 15
// 94.494 us; speedup vs baseline: 1.4440x; 1.0460x over previous
//
#include <hip/hip_runtime.h>
#include <hip/hip_bf16.h>

#define BB 32
#define CC 128
#define HH 96
#define WW 96
#define BN_EPS 1e-5f

typedef __attribute__((ext_vector_type(8))) short bf16x8_t;
typedef __attribute__((ext_vector_type(4))) float f32x4_t;
typedef __attribute__((ext_vector_type(4), aligned(4))) float f32x4u_t;
typedef __attribute__((ext_vector_type(2))) unsigned int u32x2_t;
typedef __attribute__((ext_vector_type(4))) unsigned int u32x4_t;

// ---------------------------------------------------------------------------
// Prep: W fp32 -> bf16, k-permuted (verified). BN folded to inv/bias.
// ---------------------------------------------------------------------------
__global__ __launch_bounds__(256)
void prep_kernel(const float* __restrict__ pw,
                 const float* __restrict__ g, const float* __restrict__ b,
                 const float* __restrict__ m, const float* __restrict__ v,
                 unsigned short* __restrict__ wper,
                 float* __restrict__ inv, float* __restrict__ bias)
{
    int t = blockIdx.x * 256 + threadIdx.x;
    if (t < CC * CC) {
        int o = t >> 7, cidx = t & 127;
        int kc = cidx >> 5, r = cidx & 31, gg = r >> 3, j = r & 7;
        int c = kc * 32 + gg * 4 + (j & 3) + 16 * (j >> 2);
        __hip_bfloat16 h = __float2bfloat16(pw[o * CC + c]);
        wper[o * CC + cidx] = *reinterpret_cast<unsigned short*>(&h);
    }
    if (t < CC) {
        float iv = g[t] * rsqrtf(v[t] + BN_EPS);
        inv[t] = iv;
        bias[t] = b[t] - m[t] * iv;
    }
}

// ---------------------------------------------------------------------------
// Kernel A (R15): LDS-staged depthwise 3x3. Block = (b, cs, 16-row slab).
//   Stage: 18 rows x 96 fp32 -> 6.9KB LDS tile via 2 loads + 2 ds_write_b128
//   per thread (per-thread load count so small the scheduler CANNOT sink a
//   chain — the R13/R14 pathology). Invalid halo rows written as zeros
//   (boundary handling for free). Weights are block-uniform -> s_load/SGPR.
//   Compute: thread = (row r=tid>>4, col6 cc=(tid&15)*6): 24 ds_read_b32,
//   54 FMA, 6 cvt, 3 dword stores. Zero w-halo redundancy; h-halo 1.125x.
//   Grid 24576 = 32b x 128cs x 6slab (slab fastest), XCD swizzle (8x3072).
// ---------------------------------------------------------------------------
__global__ __launch_bounds__(256, 6)
void dw_kernel(const float* __restrict__ x, const float* __restrict__ kk,
               unsigned short* __restrict__ xn)
{
    __shared__ float tile[18 * 96];      // 6912 B
    const int tid = threadIdx.x;

    const unsigned wg  = blockIdx.x;
    const unsigned bid = (wg & 7u) * 3072u + (wg >> 3);   // bijective on [0,24576)
    const int slab = bid % 6u;           // fastest -> plane-local within XCD
    const int cs   = (bid / 6u) % 128u;
    const int b    = bid / 768u;
    const int h0   = slab * 16;

    // storage -> actual channel permutation (all blockIdx-derived -> SGPR)
    const int kc = cs >> 5, rr = cs & 31, gg = rr >> 3, jj = rr & 7;
    const int c = kc * 32 + gg * 4 + (jj & 3) + 16 * (jj >> 2);

    const float* plane = x + (size_t)(b * CC + c) * (HH * WW);

    // block-uniform weights -> scalar loads, broadcast via SGPR
    const float* kp = kk + (size_t)(b * CC + c) * 9;
    const float kw0 = kp[0], kw1 = kp[1], kw2 = kp[2];
    const float kw3 = kp[3], kw4 = kp[4], kw5 = kp[5];
    const float kw6 = kp[6], kw7 = kp[7], kw8 = kp[8];

    // ---- stage 18 rows x 96 floats (432 x 16B slots; 2 slots/thread) ----
    #pragma unroll
    for (int it = 0; it < 2; ++it) {
        const int s = tid + it * 256;
        if (s < 432) {
            const int row  = s / 24;           // tile row 0..17
            const int col4 = (s % 24) * 4;     // float col 0,4,...,92
            const int hh   = h0 - 1 + row;     // image row
            f32x4_t val = (f32x4_t){0.f, 0.f, 0.f, 0.f};
            if (hh >= 0 && hh < HH)
                val = *(const f32x4_t*)(plane + (size_t)hh * WW + col4);
            *(f32x4_t*)&tile[row * 96 + col4] = val;   // 16B-aligned ds_write_b128
        }
    }
    __syncthreads();

    // ---- compute: 6 px per thread ----
    const int r  = tid >> 4;           // output row in slab, 0..15
    const int cc = (tid & 15) * 6;     // first col, 0..90

    float v[3][8];
    #pragma unroll
    for (int dr = 0; dr < 3; ++dr) {
        const float* trow = &tile[(r + dr) * 96];
        const float lv = trow[cc == 0 ? 0 : cc - 1];
        v[dr][0] = (cc == 0) ? 0.f : lv;
        #pragma unroll
        for (int i = 0; i < 6; ++i) v[dr][1 + i] = trow[cc + i];
        const float rv = trow[cc == 90 ? 95 : cc + 6];
        v[dr][7] = (cc == 90) ? 0.f : rv;
    }

    unsigned pk[3];
    #pragma unroll
    for (int pr = 0; pr < 3; ++pr) {           // pixel pairs (2j, 2j+1)
        float s0, s1;
        const int j0 = 2 * pr;
        s0 = v[0][j0] * kw0;                   const int j1 = j0 + 1;
        s0 = fmaf(v[0][j0 + 1], kw1, s0);
        s0 = fmaf(v[0][j0 + 2], kw2, s0);
        s0 = fmaf(v[1][j0],     kw3, s0);
        s0 = fmaf(v[1][j0 + 1], kw4, s0);
        s0 = fmaf(v[1][j0 + 2], kw5, s0);
        s0 = fmaf(v[2][j0],     kw6, s0);
        s0 = fmaf(v[2][j0 + 1], kw7, s0);
        s0 = fmaf(v[2][j0 + 2], kw8, s0);
        s1 = v[0][j1] * kw0;
        s1 = fmaf(v[0][j1 + 1], kw1, s1);
        s1 = fmaf(v[0][j1 + 2], kw2, s1);
        s1 = fmaf(v[1][j1],     kw3, s1);
        s1 = fmaf(v[1][j1 + 1], kw4, s1);
        s1 = fmaf(v[1][j1 + 2], kw5, s1);
        s1 = fmaf(v[2][j1],     kw6, s1);
        s1 = fmaf(v[2][j1 + 1], kw7, s1);
        s1 = fmaf(v[2][j1 + 2], kw8, s1);
        __hip_bfloat16 h0b = __float2bfloat16(s0);
        __hip_bfloat16 h1b = __float2bfloat16(s1);
        pk[pr] = (unsigned)*reinterpret_cast<unsigned short*>(&h0b)
               | ((unsigned)*reinterpret_cast<unsigned short*>(&h1b) << 16);
    }

    unsigned short* dst = xn + (size_t)(b * CC + cs) * (HH * WW)
                             + (size_t)(h0 + r) * WW + cc;     // 4B-aligned
    *reinterpret_cast<unsigned*>(dst)     = pk[0];
    *reinterpret_cast<unsigned*>(dst + 2) = pk[1];
    *reinterpret_cast<unsigned*>(dst + 4) = pk[2];
}

// ---------------------------------------------------------------------------
// Kernel B (R13 — verified): pointwise MFMA, 3 h-tiles/block, software-
// pipelined staging, nontemporal stores. Grid 768, XCD-swizzled.
// ---------------------------------------------------------------------------
__global__ __launch_bounds__(256, 3)
void pw_kernel(const unsigned short* __restrict__ xn,
               const unsigned short* __restrict__ wper,
               const float* __restrict__ invp, const float* __restrict__ biasp,
               float* __restrict__ out)
{
    __shared__ __align__(16) unsigned char xnb[128 * 256];
    const int tid = threadIdx.x;

    const unsigned wg  = blockIdx.x;
    const unsigned nid = (wg & 7u) * 96u + (wg >> 3);
    const int tw  = nid % 6u;
    const int thg = (nid / 6u) % 4u;
    const int b   = nid / 24u;
    const int w0  = tw * 16;

    const int lane   = tid & 63;
    const int wv     = tid >> 6;
    const int lo     = lane & 15;
    const int hi     = lane >> 4;
    const int o_base = wv * 32;

    bf16x8_t wfrag[2][4];
    #pragma unroll
    for (int t2 = 0; t2 < 2; ++t2)
        #pragma unroll
        for (int kc = 0; kc < 4; ++kc)
            wfrag[t2][kc] = *reinterpret_cast<const bf16x8_t*>(
                wper + (size_t)(o_base + t2 * 16 + lo) * CC + kc * 32 + hi * 8);

    float iv2[2], bs2[2];
    #pragma unroll
    for (int t2 = 0; t2 < 2; ++t2) {
        iv2[t2] = invp[o_base + t2 * 16 + lo];
        bs2[t2] = biasp[o_base + t2 * 16 + lo];
    }

    const int cs4 = tid >> 3;
    const int py  = tid & 7;
    const unsigned short* src_base =
        xn + (size_t)(b * CC + cs4 * 4) * (HH * WW) + (size_t)py * WW + w0;

    unsigned dLA[4][4], dRA[4][4], dLB[4][4], dRB[4][4];

    auto LOADREGS = [&](int t, unsigned (*dL)[4], unsigned (*dR)[4]) {
        const unsigned short* s0 = src_base + (size_t)((thg * 3 + t) * 8) * WW;
        #pragma unroll
        for (int q = 0; q < 4; ++q) {
            const unsigned short* src = s0 + (size_t)q * (HH * WW);
            u32x4_t L = *(const u32x4_t*)src;
            u32x4_t R = *(const u32x4_t*)(src + 8);
            dL[q][0]=L.x; dL[q][1]=L.y; dL[q][2]=L.z; dL[q][3]=L.w;
            dR[q][0]=R.x; dR[q][1]=R.y; dR[q][2]=R.z; dR[q][3]=R.w;
        }
    };

    auto WRITE_LDS = [&](unsigned (*dL)[4], unsigned (*dR)[4]) {
        #pragma unroll
        for (int o8 = 0; o8 < 2; ++o8) {
            #pragma unroll
            for (int j = 0; j < 4; ++j) {
                const unsigned d0 = o8 ? dR[0][j] : dL[0][j];
                const unsigned d1 = o8 ? dR[1][j] : dL[1][j];
                const unsigned d2 = o8 ? dR[2][j] : dL[2][j];
                const unsigned d3 = o8 ? dR[3][j] : dL[3][j];
                u32x2_t we, wo;
                we.x = __builtin_amdgcn_perm(d1, d0, 0x05040100u);
                we.y = __builtin_amdgcn_perm(d3, d2, 0x05040100u);
                wo.x = __builtin_amdgcn_perm(d1, d0, 0x07060302u);
                wo.y = __builtin_amdgcn_perm(d3, d2, 0x07060302u);
                const int pe = py * 16 + o8 * 8 + 2 * j;
                const int po = pe + 1;
                *reinterpret_cast<u32x2_t*>(&xnb[(unsigned)pe * 256 +
                    (((unsigned)cs4 * 8) ^ (((unsigned)pe & 7u) << 4))]) = we;
                *reinterpret_cast<u32x2_t*>(&xnb[(unsigned)po * 256 +
                    (((unsigned)cs4 * 8) ^ (((unsigned)po & 7u) << 4))]) = wo;
            }
        }
    };

    auto COMPUTE = [&](int t) {
        const int h0 = (thg * 3 + t) * 8;
        f32x4_t acc[8][2];
        #pragma unroll
        for (int pt = 0; pt < 8; ++pt) {
            acc[pt][0] = (f32x4_t){0.f, 0.f, 0.f, 0.f};
            acc[pt][1] = (f32x4_t){0.f, 0.f, 0.f, 0.f};
        }
        #pragma unroll
        for (int pt = 0; pt < 8; ++pt) {
            const unsigned rowbase = (unsigned)(pt * 16 + lo) * 256;
            const unsigned sw = (unsigned)((lo & 7) << 4);
            #pragma unroll
            for (int kc = 0; kc < 4; ++kc) {
                bf16x8_t xfrag = *reinterpret_cast<const bf16x8_t*>(
                    &xnb[rowbase + (((unsigned)(kc * 64 + hi * 16)) ^ sw)]);
                acc[pt][0] = __builtin_amdgcn_mfma_f32_16x16x32_bf16(
                    xfrag, wfrag[0][kc], acc[pt][0], 0, 0, 0);
                acc[pt][1] = __builtin_amdgcn_mfma_f32_16x16x32_bf16(
                    xfrag, wfrag[1][kc], acc[pt][1], 0, 0, 0);
            }
        }
        #pragma unroll
        for (int pt = 0; pt < 8; ++pt) {
            const int hrow = h0 + pt;
            #pragma unroll
            for (int t2 = 0; t2 < 2; ++t2) {
                const int o = o_base + t2 * 16 + lo;
                f32x4_t vv;
                #pragma unroll
                for (int rix = 0; rix < 4; ++rix)
                    vv[rix] = fmaxf(fmaf(acc[pt][t2][rix], iv2[t2], bs2[t2]), 0.f);
                __builtin_nontemporal_store(vv, reinterpret_cast<f32x4_t*>(
                    out + ((size_t)(b * CC + o) * HH + hrow) * WW + w0 + hi * 4));
            }
        }
    };

    LOADREGS(0, dLA, dRA);
    WRITE_LDS(dLA, dRA);
    LOADREGS(1, dLB, dRB);
    __syncthreads();
    COMPUTE(0);
    __syncthreads();
    WRITE_LDS(dLB, dRB);
    LOADREGS(2, dLA, dRA);
    __syncthreads();
    COMPUTE(1);
    __syncthreads();
    WRITE_LDS(dLA, dRA);
    __syncthreads();
    COMPUTE(2);
}

// ---------------------------------------------------------------------------
// Fallback (ws too small): R5 fused kernel.
// ---------------------------------------------------------------------------
__global__ __launch_bounds__(256, 3)
void fused_main(const float* __restrict__ x, const float* __restrict__ kk,
                const unsigned short* __restrict__ wper,
                const float* __restrict__ invp, const float* __restrict__ biasp,
                float* __restrict__ out)
{
    __shared__ __align__(16) unsigned char xnb[128 * 256];
    const int tid = threadIdx.x;
    const unsigned wg  = blockIdx.x;
    const unsigned nid = (wg & 7u) * 288u + (wg >> 3);
    const int bx = nid % 6u;
    const int by = (nid / 6u) % 12u;
    const int bb = nid / 72u;
    const int w0 = bx * 16;
    const int h0 = by * 8;
    {
        const int wq = tid & 3;
        const int cp = tid >> 2;
        const int s  = cp << 1;
        const int kc = s >> 5, rr = s & 31, gg = rr >> 3, jj = rr & 7;
        const int cA = kc * 32 + gg * 4 + (jj & 3) + 16 * (jj >> 2);
        const int gw = w0 + wq * 4;
        const bool l_edge = (gw == 0);
        const bool r_edge = (gw + 4 >= WW);
        const float* planeA = x + (size_t)(bb * CC + cA) * (HH * WW);
        float kwA[9], kwB[9];
        {
            const float* kp = kk + (size_t)(bb * CC + cA) * 9;
            f32x4u_t q0 = *(const f32x4u_t*)(kp + 0);
            f32x4u_t q1 = *(const f32x4u_t*)(kp + 4);
            f32x4u_t q2 = *(const f32x4u_t*)(kp + 8);
            f32x4u_t q3 = *(const f32x4u_t*)(kp + 12);
            float     e16 = kp[16], e17 = kp[17];
            kwA[0]=q0.x; kwA[1]=q0.y; kwA[2]=q0.z; kwA[3]=q0.w;
            kwA[4]=q1.x; kwA[5]=q1.y; kwA[6]=q1.z; kwA[7]=q1.w;
            kwA[8]=q2.x;
            kwB[0]=q2.y; kwB[1]=q2.z; kwB[2]=q2.w;
            kwB[3]=q3.x; kwB[4]=q3.y; kwB[5]=q3.z; kwB[6]=q3.w;
            kwB[7]=e16;  kwB[8]=e17;
        }
        float xd[2][10][6];
        #pragma unroll
        for (int q = 0; q < 2; ++q) {
            const float* plane = planeA + q * (HH * WW);
            #pragma unroll
            for (int r = 0; r < 10; ++r) {
                const int row = h0 - 1 + r;
                const bool valid = (row >= 0) && (row < HH);
                const int rrow = row < 0 ? 0 : (row >= HH ? HH - 1 : row);
                const float* rp = plane + rrow * WW + gw;
                f32x4_t M = *(const f32x4_t*)rp;
                float vl = rp[l_edge ? 0 : -1];
                float vr = rp[r_edge ? 3 : 4];
                xd[q][r][0] = (valid && !l_edge) ? vl : 0.f;
                xd[q][r][1] = valid ? M.x : 0.f;
                xd[q][r][2] = valid ? M.y : 0.f;
                xd[q][r][3] = valid ? M.z : 0.f;
                xd[q][r][4] = valid ? M.w : 0.f;
                xd[q][r][5] = (valid && !r_edge) ? vr : 0.f;
            }
        }
        #pragma unroll
        for (int py = 0; py < 8; ++py) {
            #pragma unroll
            for (int i = 0; i < 4; ++i) {
                float sA = 0.f, sB = 0.f;
                #pragma unroll
                for (int t = 0; t < 3; ++t) {
                    sA = fmaf(xd[0][py + 0][i + t], kwA[t],     sA);
                    sA = fmaf(xd[0][py + 1][i + t], kwA[3 + t], sA);
                    sA = fmaf(xd[0][py + 2][i + t], kwA[6 + t], sA);
                    sB = fmaf(xd[1][py + 0][i + t], kwB[t],     sB);
                    sB = fmaf(xd[1][py + 1][i + t], kwB[3 + t], sB);
                    sB = fmaf(xd[1][py + 2][i + t], kwB[6 + t], sB);
                }
                __hip_bfloat16 hA = __float2bfloat16(sA);
                __hip_bfloat16 hB = __float2bfloat16(sB);
                unsigned pk = (unsigned)*reinterpret_cast<unsigned short*>(&hA)
                            | ((unsigned)*reinterpret_cast<unsigned short*>(&hB) << 16);
                const int p = py * 16 + wq * 4 + i;
                const unsigned boff = ((unsigned)(cp << 2)) ^ (((unsigned)p & 7u) << 4);
                *reinterpret_cast<unsigned*>(&xnb[(unsigned)p * 256 + boff]) = pk;
            }
        }
    }
    __syncthreads();
    {
        const int lane   = tid & 63;
        const int wv     = tid >> 6;
        const int lo     = lane & 15;
        const int hi     = lane >> 4;
        const int o_base = wv * 32;
        bf16x8_t afrag[2][4];
        #pragma unroll
        for (int t2 = 0; t2 < 2; ++t2)
            #pragma unroll
            for (int kc = 0; kc < 4; ++kc)
                afrag[t2][kc] = *reinterpret_cast<const bf16x8_t*>(
                    wper + (size_t)(o_base + t2 * 16 + lo) * CC + kc * 32 + hi * 8);
        f32x4_t acc[8][2];
        #pragma unroll
        for (int pt = 0; pt < 8; ++pt) {
            acc[pt][0] = (f32x4_t){0.f, 0.f, 0.f, 0.f};
            acc[pt][1] = (f32x4_t){0.f, 0.f, 0.f, 0.f};
        }
        #pragma unroll
        for (int pt = 0; pt < 8; ++pt) {
            const unsigned rowbase = (unsigned)(pt * 16 + lo) * 256;
            const unsigned sw = (unsigned)((lo & 7) << 4);
            #pragma unroll
            for (int kc = 0; kc < 4; ++kc) {
                bf16x8_t bfrag = *reinterpret_cast<const bf16x8_t*>(
                    &xnb[rowbase + (((unsigned)(kc * 64 + hi * 16)) ^ sw)]);
                acc[pt][0] = __builtin_amdgcn_mfma_f32_16x16x32_bf16(
                    afrag[0][kc], bfrag, acc[pt][0], 0, 0, 0);
                acc[pt][1] = __builtin_amdgcn_mfma_f32_16x16x32_bf16(
                    afrag[1][kc], bfrag, acc[pt][1], 0, 0, 0);
            }
        }
        float iv[2][4], bs[2][4];
        #pragma unroll
        for (int t2 = 0; t2 < 2; ++t2)
            #pragma unroll
            for (int r = 0; r < 4; ++r) {
                const int o = o_base + t2 * 16 + hi * 4 + r;
                iv[t2][r] = invp[o];
                bs[t2][r] = biasp[o];
            }
        #pragma unroll
        for (int pt = 0; pt < 8; ++pt) {
            const int hrow = h0 + pt;
            #pragma unroll
            for (int t2 = 0; t2 < 2; ++t2) {
                #pragma unroll
                for (int r = 0; r < 4; ++r) {
                    const int o = o_base + t2 * 16 + hi * 4 + r;
                    float val = fmaf(acc[pt][t2][r], iv[t2][r], bs[t2][r]);
                    val = fmaxf(val, 0.f);
                    out[((size_t)(bb * CC + o) * HH + hrow) * WW + w0 + lo] = val;
                }
            }
        }
    }
}

extern "C" void kernel_launch(void* const* d_in, const int* in_sizes, int n_in,
                              void* d_out, int out_size, void* d_ws, size_t ws_size,
                              hipStream_t stream) {
    const float* x   = (const float*)d_in[0];
    const float* kk  = (const float*)d_in[1];
    const float* pwt = (const float*)d_in[2];
    const float* g   = (const float*)d_in[3];
    const float* b   = (const float*)d_in[4];
    const float* m   = (const float*)d_in[5];
    const float* v   = (const float*)d_in[6];
    float* out = (float*)d_out;

    unsigned short* wper = (unsigned short*)d_ws;                 // 32 KB
    float* inv  = (float*)((char*)d_ws + 32768);                  // 512 B
    float* bias = (float*)((char*)d_ws + 32768 + 512);            // 512 B
    unsigned short* xn = (unsigned short*)((char*)d_ws + 36864);  // 75.5 MB
    const size_t need = 36864 + (size_t)BB * CC * HH * WW * 2;

    prep_kernel<<<64, 256, 0, stream>>>(pwt, g, b, m, v, wper, inv, bias);
    if (ws_size >= need) {
        dw_kernel<<<dim3(24576), 256, 0, stream>>>(x, kk, xn);
        pw_kernel<<<dim3(768), 256, 0, stream>>>(xn, wper, inv, bias, out);
    } else {
        fused_main<<<dim3(2304), 256, 0, stream>>>(x, kk, wper, inv, bias, out);
    }
}